// Round 6
// baseline (571.435 us; speedup 1.0000x reference)
//
#include <hip/hip_runtime.h>
#include <hip/hip_bf16.h>

__device__ float g_pre_static[8 * 1024 * 1024];  // fallback scratch (32 MB)
__device__ int   g_f32[13];                      // per-array: 1 = f32, 0 = bf16

__device__ __forceinline__ float bfu2f(unsigned short u) {
    return __uint_as_float(((unsigned)u) << 16);
}
__device__ __forceinline__ float decode(const void* p, long idx, int f32in) {
    return f32in ? ((const float*)p)[idx] : bfu2f(((const unsigned short*)p)[idx]);
}
__device__ __forceinline__ float sigm(float x)  { return 1.0f/(1.0f + __expf(-x)); }
__device__ __forceinline__ float tanh_(float x) { float e = __expf(2.0f*x); return (e-1.0f)/(e+1.0f); }

// ---------------------------------------------------------------------------
// Per-array input dtype detection (robust under either dtype; has returned
// "f32" for this dataset since R2 — kept as a guard, costs ~2 us).
__global__ __launch_bounds__(64) void k_dtype(
    const void* a0, const void* a1, const void* a2, const void* a3,
    const void* a4, const void* a5, const void* a6, const void* a7,
    const void* a8, const void* a9, const void* a10, const void* a11,
    const void* a12,
    int n0, int n1, int n2, int n3, int n4, int n5, int n6, int n7,
    int n8, int n9, int n10, int n11, int n12)
{
    const void* ps[13] = {a0,a1,a2,a3,a4,a5,a6,a7,a8,a9,a10,a11,a12};
    const int   ns[13] = {n0,n1,n2,n3,n4,n5,n6,n7,n8,n9,n10,n11,n12};
    const int i = blockIdx.x;
    const unsigned short* p = (const unsigned short*)ps[i];
    int n = ns[i]; if (n > 8192) n = 8192;
    bool f32ev = false;
    for (int k = threadIdx.x; k < n; k += 64) {
        unsigned short h = p[k];
        if ((h & 0x7FFF) == 0) continue;
        unsigned e = (h >> 7) & 0xFFu;
        if (e < 0x60u || e > 0x9Fu) f32ev = true;  // impossible for real bf16 data
    }
    unsigned long long m = __ballot(f32ev);
    if (threadIdx.x == 0) g_f32[i] = (m != 0ull) ? 1 : 0;
}

// ---------------------------------------------------------------------------
// pre[t, g*H+w, b] = bias_g[w] + sum_{k<ID} x[t,b,k] * W_g[w,k]
// grid = (S, ceil(B/64)), block = 64.
// Dynamic LDS: xs[64][SP] | wsh[4H][dIn] | sbias[4H]
__global__ __launch_bounds__(64) void k_pre(
    const void* __restrict__ x_,
    const void* W0, const void* b0p,
    const void* W1, const void* b1p,
    const void* W2, const void* b2p,
    const void* W3, const void* b3p,
    float* __restrict__ pre,
    int S, int B, int ID, int H, int SP)
{
    extern __shared__ float lds[];
    const int dIn = ID + H;
    float* xs    = lds;
    float* wsh   = lds + 64*SP;
    float* sbias = wsh + 4*H*dIn;
    const int t   = blockIdx.x;
    const int tid = threadIdx.x;
    const int bb0 = blockIdx.y * 64;
    const int fx = g_f32[0];
    const int fW[4] = {g_f32[1], g_f32[4], g_f32[7], g_f32[10]};
    const int fb[4] = {g_f32[2], g_f32[5], g_f32[8], g_f32[11]};
    const void* Wp[4] = {W0, W1, W2, W3};
    const void* bp[4] = {b0p, b1p, b2p, b3p};

    for (int g = 0; g < 4; ++g)
        for (int idx = tid; idx < H*dIn; idx += 64)
            wsh[g*H*dIn + idx] = decode(Wp[g], idx, fW[g]);
    for (int idx = tid; idx < 4*H; idx += 64)
        sbias[idx] = decode(bp[idx / H], idx % H, fb[idx / H]);

    for (int r = 0; r < 64; ++r) {
        long b = (long)bb0 + r;
        if (b >= B) break;
        long rowoff = ((long)t * B + b) * ID;
        for (int c = tid; c < ID; c += 64)
            xs[r*SP + c] = decode(x_, rowoff + c, fx);
    }
    __syncthreads();

    const int b = bb0 + tid;
    if (b < B) {
        const float* xrow = &xs[tid*SP];
        for (int gw = 0; gw < 4*H; ++gw) {
            float acc = sbias[gw];
            const float* wrow = &wsh[gw*dIn];
            for (int k = 0; k < ID; ++k) acc += xrow[k] * wrow[k];
            pre[((long)t*4*H + gw)*B + b] = acc;
        }
    }
}

// ---------------------------------------------------------------------------
// Closed-form qgate (validated: brute-force state-vector sim in R4 produced a
// bit-identical trajectory):
//   expz[w < n-1] = cos(q_w) * prod_{j<=w} cos(theta_j)
//   expz[n-1]     = cos(theta_{n-1} + q_{n-1}) * prod_{j<n-1} cos(theta_j)
// Sequential LSTM recurrence: grid = ceil(B/64), block = 64, 1 thread per b.
// OUTPUT IS FLOAT32 (reference output dtype).
template<int HH>
__global__ __launch_bounds__(64) void k_rec_t(
    const float* __restrict__ pre,
    const void* W0, const void* q0,
    const void* W1, const void* q1,
    const void* W2, const void* q2,
    const void* W3, const void* q3,
    float* __restrict__ out, int S, int B, int ID)
{
    __shared__ float sWh[4*HH*HH];   // hidden part W_g[w][ID+j], row gw
    __shared__ float scq[4*HH];      // cos(q_w) for w<HH-1; raw q at w==HH-1
    const int dIn = ID + HH;
    const int tid = threadIdx.x;
    const int b   = blockIdx.x*64 + tid;
    const int fW[4] = {g_f32[1], g_f32[4], g_f32[7], g_f32[10]};
    const int fq[4] = {g_f32[3], g_f32[6], g_f32[9], g_f32[12]};
    const void* Wp[4] = {W0, W1, W2, W3};
    const void* qp[4] = {q0, q1, q2, q3};

    for (int idx = tid; idx < 4*HH*HH; idx += 64) {
        int g = idx / (HH*HH), r = idx % (HH*HH);
        int w = r / HH, j = r % HH;
        sWh[idx] = decode(Wp[g], (long)w*dIn + ID + j, fW[g]);
    }
    for (int idx = tid; idx < 4*HH; idx += 64) {
        int g = idx / HH, w = idx % HH;
        float qv = decode(qp[g], w, fq[g]);
        scq[idx] = (w < HH-1) ? __cosf(qv) : qv;
    }
    __syncthreads();
    if (b >= B) return;

    float hx[HH], cx[HH];
    #pragma unroll
    for (int w = 0; w < HH; ++w) { hx[w] = 0.0f; cx[w] = 0.0f; }

    for (int t = 0; t < S; ++t) {
        const float* pt = pre + (long)t*4*HH*B + b;
        float gate[4][HH];
        #pragma unroll
        for (int g = 0; g < 4; ++g) {
            float th[HH];
            #pragma unroll
            for (int w = 0; w < HH; ++w) {
                float a = pt[(long)(g*HH + w)*B];
                const float* wr = &sWh[(g*HH + w)*HH];
                #pragma unroll
                for (int j = 0; j < HH; ++j) a += wr[j]*hx[j];
                th[w] = a;
            }
            float cum = 1.0f;
            #pragma unroll
            for (int w = 0; w < HH-1; ++w) {
                cum *= __cosf(th[w]);
                gate[g][w] = scq[g*HH + w] * cum;
            }
            gate[g][HH-1] = cum * __cosf(th[HH-1] + scq[g*HH + HH-1]);
        }
        float* orow = out + ((long)t*B + b)*HH;
        #pragma unroll
        for (int w = 0; w < HH; ++w) {
            float fv = sigm (gate[0][w]);
            float iv = sigm (gate[1][w]);
            float gv = tanh_(gate[2][w]);
            float ov = sigm (gate[3][w]);
            cx[w] = fv*cx[w] + iv*gv;
            hx[w] = ov*tanh_(cx[w]);
            orow[w] = hx[w];
        }
    }
    float* oh = out + ((long)S*B + b)*HH;
    float* oc = out + ((long)S*B + B + b)*HH;
    #pragma unroll
    for (int w = 0; w < HH; ++w) { oh[w] = hx[w]; oc[w] = cx[w]; }
}

// Generic runtime-H fallback (H <= 32).
__global__ __launch_bounds__(64) void k_rec_g(
    const float* __restrict__ pre,
    const void* W0, const void* q0,
    const void* W1, const void* q1,
    const void* W2, const void* q2,
    const void* W3, const void* q3,
    float* __restrict__ out, int S, int B, int ID, int H)
{
    __shared__ float sWh[4*32*32];
    __shared__ float scq[4*32];
    const int dIn = ID + H;
    const int tid = threadIdx.x;
    const int b   = blockIdx.x*64 + tid;
    const int fW[4] = {g_f32[1], g_f32[4], g_f32[7], g_f32[10]};
    const int fq[4] = {g_f32[3], g_f32[6], g_f32[9], g_f32[12]};
    const void* Wp[4] = {W0, W1, W2, W3};
    const void* qp[4] = {q0, q1, q2, q3};

    for (int idx = tid; idx < 4*H*H; idx += 64) {
        int g = idx / (H*H), r = idx % (H*H);
        int w = r / H, j = r % H;
        sWh[(g*H + w)*H + j] = decode(Wp[g], (long)w*dIn + ID + j, fW[g]);
    }
    for (int idx = tid; idx < 4*H; idx += 64) {
        int g = idx / H, w = idx % H;
        float qv = decode(qp[g], w, fq[g]);
        scq[idx] = (w < H-1) ? __cosf(qv) : qv;
    }
    __syncthreads();
    if (b >= B) return;

    float hx[32], cx[32], gate[4][32], th[32];
    for (int w = 0; w < H; ++w) { hx[w] = 0.0f; cx[w] = 0.0f; }

    for (int t = 0; t < S; ++t) {
        const float* pt = pre + (long)t*4*H*B + b;
        for (int g = 0; g < 4; ++g) {
            for (int w = 0; w < H; ++w) {
                float a = pt[(long)(g*H + w)*B];
                const float* wr = &sWh[(g*H + w)*H];
                for (int j = 0; j < H; ++j) a += wr[j]*hx[j];
                th[w] = a;
            }
            float cum = 1.0f;
            for (int w = 0; w < H-1; ++w) {
                cum *= __cosf(th[w]);
                gate[g][w] = scq[g*H + w] * cum;
            }
            gate[g][H-1] = cum * __cosf(th[H-1] + scq[g*H + H-1]);
        }
        float* orow = out + ((long)t*B + b)*H;
        for (int w = 0; w < H; ++w) {
            float fv = sigm (gate[0][w]);
            float iv = sigm (gate[1][w]);
            float gv = tanh_(gate[2][w]);
            float ov = sigm (gate[3][w]);
            cx[w] = fv*cx[w] + iv*gv;
            hx[w] = ov*tanh_(cx[w]);
            orow[w] = hx[w];
        }
    }
    float* oh = out + ((long)S*B + b)*H;
    float* oc = out + ((long)S*B + B + b)*H;
    for (int w = 0; w < H; ++w) { oh[w] = hx[w]; oc[w] = cx[w]; }
}

static bool derive(long sz[13], long osz, long& S, long& B, long& ID, long& H) {
    H = sz[3];
    long dIn = (H > 0) ? sz[1] / H : 0;
    ID = dIn - H;
    long TB = (ID > 0) ? sz[0] / ID : 0;
    B = (H > 0) ? (osz / H - TB) / 2 : 0;
    S = (B > 0) ? TB / B : 0;
    return (H >= 1 && H <= 32 && ID >= 1 && B >= 1 && S >= 1 &&
            S*B == TB && (S*B + 2*B)*H == osz &&
            dIn*H == sz[1] && TB*ID == sz[0]);
}

extern "C" void kernel_launch(void* const* d_in, const int* in_sizes, int n_in,
                              void* d_out, int out_size, void* d_ws, size_t ws_size,
                              hipStream_t stream) {
    const void* x  = d_in[0];
    const void* Wf = d_in[1];  const void* bfv = d_in[2];  const void* qf = d_in[3];
    const void* Wi = d_in[4];  const void* biv = d_in[5];  const void* qi = d_in[6];
    const void* Wg = d_in[7];  const void* bgv = d_in[8];  const void* qg = d_in[9];
    const void* Wo = d_in[10]; const void* bov = d_in[11]; const void* qo = d_in[12];
    float* out = (float*)d_out;

    // Shapes: try element-counts, then byte-counts/4, then byte/2; else defaults.
    long S = 0, B = 0, ID = 0, H = 0;
    bool ok = false;
    for (int scale : {1, 4, 2}) {
        long sz[13];
        for (int i = 0; i < 13; ++i) sz[i] = (long)in_sizes[i] / scale;
        long osz = (long)out_size / scale;
        if (derive(sz, osz, S, B, ID, H)) { ok = true; break; }
    }
    if (!ok) { H = 8; ID = 64; B = 256; S = 64; }
    long dIn = ID + H;

    size_t pre_bytes = (size_t)S * 4 * H * B * sizeof(float);
    float* pre = (ws_size >= pre_bytes) ? (float*)d_ws : g_pre_static;

    int SP = (int)ID + 1;
    size_t lds_bytes = (size_t)(64*SP + 4*H*dIn + 4*H) * sizeof(float);

    k_dtype<<<dim3(13), dim3(64), 0, stream>>>(
        x, Wf, bfv, qf, Wi, biv, qi, Wg, bgv, qg, Wo, bov, qo,
        in_sizes[0], in_sizes[1], in_sizes[2], in_sizes[3],
        in_sizes[4], in_sizes[5], in_sizes[6], in_sizes[7],
        in_sizes[8], in_sizes[9], in_sizes[10], in_sizes[11], in_sizes[12]);

    k_pre<<<dim3((unsigned)S, (unsigned)((B + 63) / 64)), dim3(64), lds_bytes, stream>>>(
        x, Wf, bfv, Wi, biv, Wg, bgv, Wo, bov, pre,
        (int)S, (int)B, (int)ID, (int)H, SP);

    dim3 rg((unsigned)((B + 63) / 64));
    if (H == 8)
        k_rec_t<8><<<rg, dim3(64), 0, stream>>>(pre, Wf, qf, Wi, qi, Wg, qg, Wo, qo,
                                                out, (int)S, (int)B, (int)ID);
    else if (H == 16)
        k_rec_t<16><<<rg, dim3(64), 0, stream>>>(pre, Wf, qf, Wi, qi, Wg, qg, Wo, qo,
                                                 out, (int)S, (int)B, (int)ID);
    else
        k_rec_g<<<rg, dim3(64), 0, stream>>>(pre, Wf, qf, Wi, qi, Wg, qg, Wo, qo,
                                             out, (int)S, (int)B, (int)ID, (int)H);
}

// Round 7
// 205.425 us; speedup vs baseline: 2.7817x; 2.7817x over previous
//
#include <hip/hip_runtime.h>
#include <hip/hip_bf16.h>

__device__ float g_pre_static[8 * 1024 * 1024];  // fallback scratch (32 MB)
__device__ int   g_f32[13];                      // per-array: 1 = f32, 0 = bf16

__device__ __forceinline__ float bfu2f(unsigned short u) {
    return __uint_as_float(((unsigned)u) << 16);
}
__device__ __forceinline__ float decode(const void* p, long idx, int f32in) {
    return f32in ? ((const float*)p)[idx] : bfu2f(((const unsigned short*)p)[idx]);
}
__device__ __forceinline__ float sigm(float x)  { return 1.0f/(1.0f + __expf(-x)); }
__device__ __forceinline__ float tanh_(float x) { float e = __expf(2.0f*x); return (e-1.0f)/(e+1.0f); }

// ---------------------------------------------------------------------------
// Per-array input dtype detection (guard; returns f32 for this dataset).
__global__ __launch_bounds__(64) void k_dtype(
    const void* a0, const void* a1, const void* a2, const void* a3,
    const void* a4, const void* a5, const void* a6, const void* a7,
    const void* a8, const void* a9, const void* a10, const void* a11,
    const void* a12,
    int n0, int n1, int n2, int n3, int n4, int n5, int n6, int n7,
    int n8, int n9, int n10, int n11, int n12)
{
    const void* ps[13] = {a0,a1,a2,a3,a4,a5,a6,a7,a8,a9,a10,a11,a12};
    const int   ns[13] = {n0,n1,n2,n3,n4,n5,n6,n7,n8,n9,n10,n11,n12};
    const int i = blockIdx.x;
    const unsigned short* p = (const unsigned short*)ps[i];
    int n = ns[i]; if (n > 8192) n = 8192;
    bool f32ev = false;
    for (int k = threadIdx.x; k < n; k += 64) {
        unsigned short h = p[k];
        if ((h & 0x7FFF) == 0) continue;
        unsigned e = (h >> 7) & 0xFFu;
        if (e < 0x60u || e > 0x9Fu) f32ev = true;  // impossible for real bf16 data
    }
    unsigned long long m = __ballot(f32ev);
    if (threadIdx.x == 0) g_f32[i] = (m != 0ull) ? 1 : 0;
}

// ---------------------------------------------------------------------------
// pre layout (NEW): pre[((t*B + b)*4 + g)*H + w]  -- 4H consecutive per (t,b),
// so the recurrence reads 2 float4 per lane per step.
// grid = (S, ceil(B/64)), block = 256: tid = q*64 + bl; thread (q,bl) computes
// gate q's H outputs for batch b0+bl.
// LDS: xs[64][SP] (SP=ID+1, conflict-free) | wsh[4H][dInP] (dInP=dIn+1) | sbias
__global__ __launch_bounds__(256) void k_pre(
    const void* __restrict__ x_,
    const void* W0, const void* b0p,
    const void* W1, const void* b1p,
    const void* W2, const void* b2p,
    const void* W3, const void* b3p,
    float* __restrict__ pre,
    int S, int B, int ID, int H, int SP)
{
    extern __shared__ float lds[];
    const int dIn  = ID + H;
    const int dInP = dIn + 1;
    float* xs    = lds;                    // 64*SP
    float* wsh   = lds + 64*SP;            // 4H*dInP
    float* sbias = wsh + 4*H*dInP;         // 4H
    const int t   = blockIdx.x;
    const int tid = threadIdx.x;
    const int bl  = tid & 63;
    const int q   = tid >> 6;
    const int b0  = blockIdx.y * 64;
    const int fx = g_f32[0];
    const int fW[4] = {g_f32[1], g_f32[4], g_f32[7], g_f32[10]};
    const int fb[4] = {g_f32[2], g_f32[5], g_f32[8], g_f32[11]};
    const void* Wp[4] = {W0, W1, W2, W3};
    const void* bp[4] = {b0p, b1p, b2p, b3p};

    for (int g = 0; g < 4; ++g)
        for (int idx = tid; idx < H*dIn; idx += 256) {
            int w = idx / dIn, k = idx - w*dIn;
            wsh[(g*H + w)*dInP + k] = decode(Wp[g], idx, fW[g]);
        }
    for (int idx = tid; idx < 4*H; idx += 256)
        sbias[idx] = decode(bp[idx / H], idx % H, fb[idx / H]);

    {   // stage x rows for the 64 batch elements of this block
        int total = 64 * ID;
        for (int i = tid; i < total; i += 256) {
            int r = i / ID, c = i - r*ID;
            long bb = (long)b0 + r; if (bb >= B) bb = B - 1;
            xs[r*SP + c] = decode(x_, ((long)t*B + bb)*ID + c, fx);
        }
    }
    __syncthreads();

    const int b = b0 + bl;
    if (b < B) {
        const float* xrow = &xs[bl*SP];
        float* orow = pre + (((long)t*B + b)*4 + q)*H;
        for (int w = 0; w < H; ++w) {
            float acc = sbias[q*H + w];
            const float* wrow = &wsh[(q*H + w)*dInP];
            for (int k = 0; k < ID; ++k) acc += xrow[k] * wrow[k];
            orow[w] = acc;
        }
    }
}

// ---------------------------------------------------------------------------
// Recurrence, H==8 fast path. Closed-form qgate (validated vs state-vector
// sim in R4):
//   expz[w<7] = cos(q_w) * prod_{j<=w} cos(theta_j)
//   expz[7]   = cos(theta_7 + q_7) * prod_{j<7} cos(theta_j)
// One WAVE handles 16 batch elements; lane = g*16 + lb (g = gate, lb = local
// b). Hidden weights + q-consts live in REGISTERS. pre is prefetched one step
// ahead (2x float4). Gate exchange via __shfl within the wave.
__global__ __launch_bounds__(64) void k_rec8(
    const void* W0, const void* q0,
    const void* W1, const void* q1,
    const void* W2, const void* q2,
    const void* W3, const void* q3,
    const float* __restrict__ pre,
    float* __restrict__ out, int S, int B, int ID)
{
    const int dIn = ID + 8;
    const int tid = threadIdx.x;
    const int g   = tid >> 4;          // gate 0..3
    const int lb  = tid & 15;          // local batch
    const int b   = blockIdx.x * 16 + lb;
    const int bs  = (b < B) ? b : (B - 1);
    const int fW[4] = {g_f32[1], g_f32[4], g_f32[7], g_f32[10]};
    const int fq[4] = {g_f32[3], g_f32[6], g_f32[9], g_f32[12]};
    const void* Wp[4] = {W0, W1, W2, W3};
    const void* qp[4] = {q0, q1, q2, q3};

    // my gate's hidden weights and q-constants in registers
    float wh[8][8];
    #pragma unroll
    for (int w = 0; w < 8; ++w)
        #pragma unroll
        for (int j = 0; j < 8; ++j)
            wh[w][j] = decode(Wp[g], (long)w*dIn + ID + j, fW[g]);
    float cq[8];
    #pragma unroll
    for (int w = 0; w < 8; ++w) {
        float qv = decode(qp[g], w, fq[g]);
        cq[w] = (w < 7) ? __cosf(qv) : qv;
    }
    // branchless activation: gate 2 uses tanh(x) = 2*sigm(2x) - 1
    const float ascl = (g == 2) ? 2.0f : 1.0f;
    const float aoff = (g == 2) ? -1.0f : 0.0f;

    float hx[8], cx[8];
    #pragma unroll
    for (int w = 0; w < 8; ++w) { hx[w] = 0.0f; cx[w] = 0.0f; }

    // prefetch t = 0
    const float4* pp = (const float4*)(pre + (((long)0*B + bs)*4 + g)*8);
    float4 pva = pp[0], pvb = pp[1];

    for (int t = 0; t < S; ++t) {
        // issue next step's loads now; waited on only at the copy below
        int tn = (t + 1 < S) ? (t + 1) : t;
        const float4* pn = (const float4*)(pre + (((long)tn*B + bs)*4 + g)*8);
        float4 pna = pn[0], pnb = pn[1];

        float pv[8] = {pva.x, pva.y, pva.z, pva.w, pvb.x, pvb.y, pvb.z, pvb.w};
        float th[8];
        #pragma unroll
        for (int w = 0; w < 8; ++w) {
            float a = pv[w];
            #pragma unroll
            for (int j = 0; j < 8; ++j) a += wh[w][j]*hx[j];
            th[w] = a;
        }
        float cum = 1.0f, gt[8];
        #pragma unroll
        for (int w = 0; w < 7; ++w) {
            cum *= __cosf(th[w]);
            gt[w] = cq[w] * cum;
        }
        gt[7] = cum * __cosf(th[7] + cq[7]);

        float act[8];
        #pragma unroll
        for (int w = 0; w < 8; ++w)
            act[w] = ascl * sigm(ascl * gt[w]) + aoff;

        // exchange the 4 gates for my batch element (lanes lb, 16+lb, 32+lb, 48+lb)
        #pragma unroll
        for (int w = 0; w < 8; ++w) {
            float fv = __shfl(act[w], lb,      64);
            float iv = __shfl(act[w], 16 + lb, 64);
            float gv = __shfl(act[w], 32 + lb, 64);
            float ov = __shfl(act[w], 48 + lb, 64);
            cx[w] = fv*cx[w] + iv*gv;
            hx[w] = ov*tanh_(cx[w]);
        }

        if (b < B) {   // lane stores wires 2g, 2g+1 (8B-aligned float2)
            float2 st = make_float2(hx[2*g], hx[2*g + 1]);
            *(float2*)(out + ((long)t*B + b)*8 + 2*g) = st;
        }
        pva = pna; pvb = pnb;
    }
    if (b < B) {
        float2 sh = make_float2(hx[2*g], hx[2*g + 1]);
        float2 sc = make_float2(cx[2*g], cx[2*g + 1]);
        *(float2*)(out + ((long)S*B + b)*8 + 2*g)     = sh;
        *(float2*)(out + ((long)S*B + B + b)*8 + 2*g) = sc;
    }
}

// ---------------------------------------------------------------------------
// Generic runtime-H fallback (H <= 32), one thread per b, reads NEW pre layout.
__global__ __launch_bounds__(64) void k_rec_g(
    const float* __restrict__ pre,
    const void* W0, const void* q0,
    const void* W1, const void* q1,
    const void* W2, const void* q2,
    const void* W3, const void* q3,
    float* __restrict__ out, int S, int B, int ID, int H)
{
    __shared__ float sWh[4*32*32];
    __shared__ float scq[4*32];
    const int dIn = ID + H;
    const int tid = threadIdx.x;
    const int b   = blockIdx.x*64 + tid;
    const int fW[4] = {g_f32[1], g_f32[4], g_f32[7], g_f32[10]};
    const int fq[4] = {g_f32[3], g_f32[6], g_f32[9], g_f32[12]};
    const void* Wp[4] = {W0, W1, W2, W3};
    const void* qp[4] = {q0, q1, q2, q3};

    for (int idx = tid; idx < 4*H*H; idx += 64) {
        int g = idx / (H*H), r = idx % (H*H);
        int w = r / H, j = r % H;
        sWh[(g*H + w)*H + j] = decode(Wp[g], (long)w*dIn + ID + j, fW[g]);
    }
    for (int idx = tid; idx < 4*H; idx += 64) {
        int g = idx / H, w = idx % H;
        float qv = decode(qp[g], w, fq[g]);
        scq[idx] = (w < H-1) ? __cosf(qv) : qv;
    }
    __syncthreads();
    if (b >= B) return;

    float hx[32], cx[32], gate[4][32], th[32];
    for (int w = 0; w < H; ++w) { hx[w] = 0.0f; cx[w] = 0.0f; }

    for (int t = 0; t < S; ++t) {
        const float* pt = pre + ((long)t*B + b)*4*H;   // 4H consecutive floats
        for (int g = 0; g < 4; ++g) {
            for (int w = 0; w < H; ++w) {
                float a = pt[g*H + w];
                const float* wr = &sWh[(g*H + w)*H];
                for (int j = 0; j < H; ++j) a += wr[j]*hx[j];
                th[w] = a;
            }
            float cum = 1.0f;
            for (int w = 0; w < H-1; ++w) {
                cum *= __cosf(th[w]);
                gate[g][w] = scq[g*H + w] * cum;
            }
            gate[g][H-1] = cum * __cosf(th[H-1] + scq[g*H + H-1]);
        }
        float* orow = out + ((long)t*B + b)*H;
        for (int w = 0; w < H; ++w) {
            float fv = sigm (gate[0][w]);
            float iv = sigm (gate[1][w]);
            float gv = tanh_(gate[2][w]);
            float ov = sigm (gate[3][w]);
            cx[w] = fv*cx[w] + iv*gv;
            hx[w] = ov*tanh_(cx[w]);
            orow[w] = hx[w];
        }
    }
    float* oh = out + ((long)S*B + b)*H;
    float* oc = out + ((long)S*B + B + b)*H;
    for (int w = 0; w < H; ++w) { oh[w] = hx[w]; oc[w] = cx[w]; }
}

static bool derive(long sz[13], long osz, long& S, long& B, long& ID, long& H) {
    H = sz[3];
    long dIn = (H > 0) ? sz[1] / H : 0;
    ID = dIn - H;
    long TB = (ID > 0) ? sz[0] / ID : 0;
    B = (H > 0) ? (osz / H - TB) / 2 : 0;
    S = (B > 0) ? TB / B : 0;
    return (H >= 1 && H <= 32 && ID >= 1 && B >= 1 && S >= 1 &&
            S*B == TB && (S*B + 2*B)*H == osz &&
            dIn*H == sz[1] && TB*ID == sz[0]);
}

extern "C" void kernel_launch(void* const* d_in, const int* in_sizes, int n_in,
                              void* d_out, int out_size, void* d_ws, size_t ws_size,
                              hipStream_t stream) {
    const void* x  = d_in[0];
    const void* Wf = d_in[1];  const void* bfv = d_in[2];  const void* qf = d_in[3];
    const void* Wi = d_in[4];  const void* biv = d_in[5];  const void* qi = d_in[6];
    const void* Wg = d_in[7];  const void* bgv = d_in[8];  const void* qg = d_in[9];
    const void* Wo = d_in[10]; const void* bov = d_in[11]; const void* qo = d_in[12];
    float* out = (float*)d_out;

    long S = 0, B = 0, ID = 0, H = 0;
    bool ok = false;
    for (int scale : {1, 4, 2}) {
        long sz[13];
        for (int i = 0; i < 13; ++i) sz[i] = (long)in_sizes[i] / scale;
        long osz = (long)out_size / scale;
        if (derive(sz, osz, S, B, ID, H)) { ok = true; break; }
    }
    if (!ok) { H = 8; ID = 64; B = 256; S = 64; }
    long dIn = ID + H;

    size_t pre_bytes = (size_t)S * 4 * H * B * sizeof(float);
    float* pre = (ws_size >= pre_bytes) ? (float*)d_ws : g_pre_static;

    int SP = (int)ID + 1;
    size_t lds_bytes = (size_t)(64*SP + 4*H*(dIn + 1) + 4*H) * sizeof(float);

    k_dtype<<<dim3(13), dim3(64), 0, stream>>>(
        x, Wf, bfv, qf, Wi, biv, qi, Wg, bgv, qg, Wo, bov, qo,
        in_sizes[0], in_sizes[1], in_sizes[2], in_sizes[3],
        in_sizes[4], in_sizes[5], in_sizes[6], in_sizes[7],
        in_sizes[8], in_sizes[9], in_sizes[10], in_sizes[11], in_sizes[12]);

    k_pre<<<dim3((unsigned)S, (unsigned)((B + 63) / 64)), dim3(256), lds_bytes, stream>>>(
        x, Wf, bfv, Wi, biv, Wg, bgv, Wo, bov, pre,
        (int)S, (int)B, (int)ID, (int)H, SP);

    if (H == 8) {
        k_rec8<<<dim3((unsigned)((B + 15) / 16)), dim3(64), 0, stream>>>(
            Wf, qf, Wi, qi, Wg, qg, Wo, qo, pre, out, (int)S, (int)B, (int)ID);
    } else {
        k_rec_g<<<dim3((unsigned)((B + 63) / 64)), dim3(64), 0, stream>>>(
            pre, Wf, qf, Wi, qi, Wg, qg, Wo, qo, out, (int)S, (int)B, (int)ID, (int)H);
    }
}

// Round 8
// 179.963 us; speedup vs baseline: 3.1753x; 1.1415x over previous
//
#include <hip/hip_runtime.h>
#include <hip/hip_bf16.h>

__device__ float g_pre_static[8 * 1024 * 1024];  // fallback scratch (32 MB)
__device__ int   g_f32[13];                      // per-array: 1 = f32, 0 = bf16

__device__ __forceinline__ float bfu2f(unsigned short u) {
    return __uint_as_float(((unsigned)u) << 16);
}
__device__ __forceinline__ float decode(const void* p, long idx, int f32in) {
    return f32in ? ((const float*)p)[idx] : bfu2f(((const unsigned short*)p)[idx]);
}
__device__ __forceinline__ float sigm(float x)  { return 1.0f/(1.0f + __expf(-x)); }
__device__ __forceinline__ float tanh_(float x) { float e = __expf(2.0f*x); return (e-1.0f)/(e+1.0f); }

// ---------------------------------------------------------------------------
// Per-array input dtype detection (guard; returns f32 for this dataset).
__global__ __launch_bounds__(256) void k_dtype(
    const void* a0, const void* a1, const void* a2, const void* a3,
    const void* a4, const void* a5, const void* a6, const void* a7,
    const void* a8, const void* a9, const void* a10, const void* a11,
    const void* a12,
    int n0, int n1, int n2, int n3, int n4, int n5, int n6, int n7,
    int n8, int n9, int n10, int n11, int n12)
{
    const void* ps[13] = {a0,a1,a2,a3,a4,a5,a6,a7,a8,a9,a10,a11,a12};
    const int   ns[13] = {n0,n1,n2,n3,n4,n5,n6,n7,n8,n9,n10,n11,n12};
    const int i = blockIdx.x;
    const unsigned short* p = (const unsigned short*)ps[i];
    int n = ns[i]; if (n > 2048) n = 2048;
    bool f32ev = false;
    for (int k = threadIdx.x; k < n; k += 256) {
        unsigned short h = p[k];
        if ((h & 0x7FFF) == 0) continue;
        unsigned e = (h >> 7) & 0xFFu;
        if (e < 0x60u || e > 0x9Fu) f32ev = true;  // impossible for real bf16 data
    }
    __syncthreads();
    __shared__ int any;
    if (threadIdx.x == 0) any = 0;
    __syncthreads();
    if (f32ev) any = 1;
    __syncthreads();
    if (threadIdx.x == 0) g_f32[i] = any;
}

// ---------------------------------------------------------------------------
// Specialized pre-GEMM, H == 8, ID == IDD (compile-time).
// pre layout: pre[((t*B + b)*4 + g)*8 + w]  (32 consecutive floats per (t,b)).
// grid = (S, ceil(B/64)), block = 64 (one thread per b, all 32 outputs).
template<int IDD>
__global__ __launch_bounds__(64) void k_pre8(
    const void* __restrict__ x_,
    const void* W0, const void* b0p,
    const void* W1, const void* b1p,
    const void* W2, const void* b2p,
    const void* W3, const void* b3p,
    float* __restrict__ pre, int S, int B)
{
    constexpr int DIN = IDD + 8;
    __shared__ float wsh[32 * IDD];   // row gw = g*8+w, col k (broadcast reads)
    __shared__ float sb32[32];
    const int t   = blockIdx.x;
    const int tid = threadIdx.x;
    const long b  = (long)blockIdx.y * 64 + tid;
    const int fx = g_f32[0];
    const int fW[4] = {g_f32[1], g_f32[4], g_f32[7], g_f32[10]};
    const int fb[4] = {g_f32[2], g_f32[5], g_f32[8], g_f32[11]};
    const void* Wp[4] = {W0, W1, W2, W3};
    const void* bp[4] = {b0p, b1p, b2p, b3p};

    #pragma unroll
    for (int it = 0; it < (32*IDD)/64; ++it) {
        int idx = it*64 + tid;
        int gw = idx / IDD, k = idx % IDD;          // IDD compile-time
        wsh[idx] = decode(Wp[gw >> 3], (gw & 7)*DIN + k, fW[gw >> 3]);
    }
    if (tid < 32) sb32[tid] = decode(bp[tid >> 3], tid & 7, fb[tid >> 3]);
    __syncthreads();

    if (b >= B) return;
    float xr[IDD];
    const long ro = ((long)t*B + b)*IDD;
    if (fx) {
        const float4* xv = (const float4*)((const float*)x_ + ro);
        #pragma unroll
        for (int i = 0; i < IDD/4; ++i) {
            float4 v = xv[i];
            xr[4*i] = v.x; xr[4*i+1] = v.y; xr[4*i+2] = v.z; xr[4*i+3] = v.w;
        }
    } else {
        const uint4* xv = (const uint4*)((const unsigned short*)x_ + ro);
        #pragma unroll
        for (int i = 0; i < IDD/8; ++i) {
            uint4 v = xv[i];
            const unsigned short* hp = (const unsigned short*)&v;
            #pragma unroll
            for (int j = 0; j < 8; ++j) xr[8*i + j] = bfu2f(hp[j]);
        }
    }

    float acc[32];
    #pragma unroll
    for (int gw = 0; gw < 32; ++gw) {
        float a = sb32[gw];
        const float4* wr = (const float4*)&wsh[gw*IDD];   // LDS broadcast
        #pragma unroll
        for (int k4 = 0; k4 < IDD/4; ++k4) {
            float4 wv = wr[k4];
            a += xr[4*k4]*wv.x + xr[4*k4+1]*wv.y + xr[4*k4+2]*wv.z + xr[4*k4+3]*wv.w;
        }
        acc[gw] = a;
    }
    float4* op = (float4*)(pre + ((long)t*B + b)*32);
    #pragma unroll
    for (int i = 0; i < 8; ++i)
        op[i] = make_float4(acc[4*i], acc[4*i+1], acc[4*i+2], acc[4*i+3]);
}

// ---------------------------------------------------------------------------
// Generic pre-GEMM fallback (runtime ID/H), writes the same pre layout.
__global__ __launch_bounds__(256) void k_pre_gen(
    const void* __restrict__ x_,
    const void* W0, const void* b0p,
    const void* W1, const void* b1p,
    const void* W2, const void* b2p,
    const void* W3, const void* b3p,
    float* __restrict__ pre,
    int S, int B, int ID, int H, int SP)
{
    extern __shared__ float lds[];
    const int dIn  = ID + H;
    const int dInP = dIn + 1;
    float* xs    = lds;
    float* wsh   = lds + 64*SP;
    float* sbias = wsh + 4*H*dInP;
    const int t   = blockIdx.x;
    const int tid = threadIdx.x;
    const int bl  = tid & 63;
    const int q   = tid >> 6;
    const int b0  = blockIdx.y * 64;
    const int fx = g_f32[0];
    const int fW[4] = {g_f32[1], g_f32[4], g_f32[7], g_f32[10]};
    const int fb[4] = {g_f32[2], g_f32[5], g_f32[8], g_f32[11]};
    const void* Wp[4] = {W0, W1, W2, W3};
    const void* bp[4] = {b0p, b1p, b2p, b3p};

    for (int g = 0; g < 4; ++g)
        for (int idx = tid; idx < H*dIn; idx += 256) {
            int w = idx / dIn, k = idx - w*dIn;
            wsh[(g*H + w)*dInP + k] = decode(Wp[g], idx, fW[g]);
        }
    for (int idx = tid; idx < 4*H; idx += 256)
        sbias[idx] = decode(bp[idx / H], idx % H, fb[idx / H]);

    {
        int total = 64 * ID;
        for (int i = tid; i < total; i += 256) {
            int r = i / ID, c = i - r*ID;
            long bb = (long)b0 + r; if (bb >= B) bb = B - 1;
            xs[r*SP + c] = decode(x_, ((long)t*B + bb)*ID + c, fx);
        }
    }
    __syncthreads();

    const int b = b0 + bl;
    if (b < B) {
        const float* xrow = &xs[bl*SP];
        float* orow = pre + (((long)t*B + b)*4 + q)*H;
        for (int w = 0; w < H; ++w) {
            float acc = sbias[q*H + w];
            const float* wrow = &wsh[(q*H + w)*dInP];
            for (int k = 0; k < ID; ++k) acc += xrow[k] * wrow[k];
            orow[w] = acc;
        }
    }
}

// ---------------------------------------------------------------------------
// Recurrence, H==8 fast path. Closed-form qgate (validated vs state-vector
// sim in R4):
//   expz[w<7] = cos(q_w) * prod_{j<=w} cos(theta_j)
//   expz[7]   = cos(theta_7 + q_7) * prod_{j<7} cos(theta_j)
// One WAVE = 16 batch elements; lane = g*16 + lb. Weights/q in registers.
// pre prefetched through a 4-deep register pipeline (8 loads in flight).
__global__ __launch_bounds__(64) void k_rec8(
    const void* W0, const void* q0,
    const void* W1, const void* q1,
    const void* W2, const void* q2,
    const void* W3, const void* q3,
    const float* __restrict__ pre,
    float* __restrict__ out, int S, int B, int ID)
{
    const int dIn = ID + 8;
    const int tid = threadIdx.x;
    const int g   = tid >> 4;
    const int lb  = tid & 15;
    const int b   = blockIdx.x * 16 + lb;
    const int bs  = (b < B) ? b : (B - 1);
    const int fW[4] = {g_f32[1], g_f32[4], g_f32[7], g_f32[10]};
    const int fq[4] = {g_f32[3], g_f32[6], g_f32[9], g_f32[12]};
    const void* Wp[4] = {W0, W1, W2, W3};
    const void* qp[4] = {q0, q1, q2, q3};

    float wh[8][8];
    #pragma unroll
    for (int w = 0; w < 8; ++w)
        #pragma unroll
        for (int j = 0; j < 8; ++j)
            wh[w][j] = decode(Wp[g], (long)w*dIn + ID + j, fW[g]);
    float cq[8];
    #pragma unroll
    for (int w = 0; w < 8; ++w) {
        float qv = decode(qp[g], w, fq[g]);
        cq[w] = (w < 7) ? __cosf(qv) : qv;
    }
    const float ascl = (g == 2) ? 2.0f : 1.0f;   // gate g: tanh = 2*sigm(2x)-1
    const float aoff = (g == 2) ? -1.0f : 0.0f;

    float hx[8], cx[8];
    #pragma unroll
    for (int w = 0; w < 8; ++w) { hx[w] = 0.0f; cx[w] = 0.0f; }

    const float4* base = (const float4*)(pre + ((long)bs*4 + g)*8);
    const long tstep = (long)B * 8;              // float4 units per t

    float4 pa[4], pb[4];
    #pragma unroll
    for (int d = 0; d < 4; ++d) {
        int tt = (d < S) ? d : (S - 1);
        pa[d] = base[(long)tt*tstep];
        pb[d] = base[(long)tt*tstep + 1];
    }

    auto step = [&](const float pv[8], int t) {
        float th[8];
        #pragma unroll
        for (int w = 0; w < 8; ++w) {
            float a = pv[w];
            #pragma unroll
            for (int j = 0; j < 8; ++j) a += wh[w][j]*hx[j];
            th[w] = a;
        }
        float co[8];
        #pragma unroll
        for (int w = 0; w < 7; ++w) co[w] = __cosf(th[w]);
        co[7] = __cosf(th[7] + cq[7]);
        float cum = 1.0f, gt[8];
        #pragma unroll
        for (int w = 0; w < 7; ++w) {
            cum *= co[w];
            gt[w] = cq[w] * cum;
        }
        gt[7] = cum * co[7];
        float act[8];
        #pragma unroll
        for (int w = 0; w < 8; ++w)
            act[w] = ascl * sigm(ascl * gt[w]) + aoff;
        #pragma unroll
        for (int w = 0; w < 8; ++w) {
            float fv = __shfl(act[w], lb,      64);
            float iv = __shfl(act[w], 16 + lb, 64);
            float gv = __shfl(act[w], 32 + lb, 64);
            float ov = __shfl(act[w], 48 + lb, 64);
            cx[w] = fv*cx[w] + iv*gv;
            hx[w] = ov*tanh_(cx[w]);
        }
        if (b < B) {
            float2 st = make_float2(hx[2*g], hx[2*g + 1]);
            *(float2*)(out + ((long)t*B + b)*8 + 2*g) = st;
        }
    };

    const int S4 = S & ~3;
    for (int t0 = 0; t0 < S4; t0 += 4) {
        #pragma unroll
        for (int d = 0; d < 4; ++d) {
            const int t = t0 + d;
            float pv[8] = {pa[d].x, pa[d].y, pa[d].z, pa[d].w,
                           pb[d].x, pb[d].y, pb[d].z, pb[d].w};
            int tn = t + 4; if (tn >= S) tn = S - 1;   // unused slots harmless
            pa[d] = base[(long)tn*tstep];
            pb[d] = base[(long)tn*tstep + 1];
            step(pv, t);
        }
    }
    for (int t = S4; t < S; ++t) {       // tail (S % 4): slots hold correct data
        const int d = t & 3;
        float pv[8] = {pa[d].x, pa[d].y, pa[d].z, pa[d].w,
                       pb[d].x, pb[d].y, pb[d].z, pb[d].w};
        step(pv, t);
    }

    if (b < B) {
        float2 sh = make_float2(hx[2*g], hx[2*g + 1]);
        float2 sc = make_float2(cx[2*g], cx[2*g + 1]);
        *(float2*)(out + ((long)S*B + b)*8 + 2*g)     = sh;
        *(float2*)(out + ((long)S*B + B + b)*8 + 2*g) = sc;
    }
}

// ---------------------------------------------------------------------------
// Generic runtime-H recurrence fallback (H <= 32), reads the same pre layout.
__global__ __launch_bounds__(64) void k_rec_g(
    const float* __restrict__ pre,
    const void* W0, const void* q0,
    const void* W1, const void* q1,
    const void* W2, const void* q2,
    const void* W3, const void* q3,
    float* __restrict__ out, int S, int B, int ID, int H)
{
    __shared__ float sWh[4*32*32];
    __shared__ float scq[4*32];
    const int dIn = ID + H;
    const int tid = threadIdx.x;
    const int b   = blockIdx.x*64 + tid;
    const int fW[4] = {g_f32[1], g_f32[4], g_f32[7], g_f32[10]};
    const int fq[4] = {g_f32[3], g_f32[6], g_f32[9], g_f32[12]};
    const void* Wp[4] = {W0, W1, W2, W3};
    const void* qp[4] = {q0, q1, q2, q3};

    for (int idx = tid; idx < 4*H*H; idx += 64) {
        int g = idx / (H*H), r = idx % (H*H);
        int w = r / H, j = r % H;
        sWh[(g*H + w)*H + j] = decode(Wp[g], (long)w*dIn + ID + j, fW[g]);
    }
    for (int idx = tid; idx < 4*H; idx += 64) {
        int g = idx / H, w = idx % H;
        float qv = decode(qp[g], w, fq[g]);
        scq[idx] = (w < H-1) ? __cosf(qv) : qv;
    }
    __syncthreads();
    if (b >= B) return;

    float hx[32], cx[32], gate[4][32], th[32];
    for (int w = 0; w < H; ++w) { hx[w] = 0.0f; cx[w] = 0.0f; }

    for (int t = 0; t < S; ++t) {
        const float* pt = pre + ((long)t*B + b)*4*H;
        for (int g = 0; g < 4; ++g) {
            for (int w = 0; w < H; ++w) {
                float a = pt[g*H + w];
                const float* wr = &sWh[(g*H + w)*H];
                for (int j = 0; j < H; ++j) a += wr[j]*hx[j];
                th[w] = a;
            }
            float cum = 1.0f;
            for (int w = 0; w < H-1; ++w) {
                cum *= __cosf(th[w]);
                gate[g][w] = scq[g*H + w] * cum;
            }
            gate[g][H-1] = cum * __cosf(th[H-1] + scq[g*H + H-1]);
        }
        float* orow = out + ((long)t*B + b)*H;
        for (int w = 0; w < H; ++w) {
            float fv = sigm (gate[0][w]);
            float iv = sigm (gate[1][w]);
            float gv = tanh_(gate[2][w]);
            float ov = sigm (gate[3][w]);
            cx[w] = fv*cx[w] + iv*gv;
            hx[w] = ov*tanh_(cx[w]);
            orow[w] = hx[w];
        }
    }
    float* oh = out + ((long)S*B + b)*H;
    float* oc = out + ((long)S*B + B + b)*H;
    for (int w = 0; w < H; ++w) { oh[w] = hx[w]; oc[w] = cx[w]; }
}

static bool derive(long sz[13], long osz, long& S, long& B, long& ID, long& H) {
    H = sz[3];
    long dIn = (H > 0) ? sz[1] / H : 0;
    ID = dIn - H;
    long TB = (ID > 0) ? sz[0] / ID : 0;
    B = (H > 0) ? (osz / H - TB) / 2 : 0;
    S = (B > 0) ? TB / B : 0;
    return (H >= 1 && H <= 32 && ID >= 1 && B >= 1 && S >= 1 &&
            S*B == TB && (S*B + 2*B)*H == osz &&
            dIn*H == sz[1] && TB*ID == sz[0]);
}

extern "C" void kernel_launch(void* const* d_in, const int* in_sizes, int n_in,
                              void* d_out, int out_size, void* d_ws, size_t ws_size,
                              hipStream_t stream) {
    const void* x  = d_in[0];
    const void* Wf = d_in[1];  const void* bfv = d_in[2];  const void* qf = d_in[3];
    const void* Wi = d_in[4];  const void* biv = d_in[5];  const void* qi = d_in[6];
    const void* Wg = d_in[7];  const void* bgv = d_in[8];  const void* qg = d_in[9];
    const void* Wo = d_in[10]; const void* bov = d_in[11]; const void* qo = d_in[12];
    float* out = (float*)d_out;

    long S = 0, B = 0, ID = 0, H = 0;
    bool ok = false;
    for (int scale : {1, 4, 2}) {
        long sz[13];
        for (int i = 0; i < 13; ++i) sz[i] = (long)in_sizes[i] / scale;
        long osz = (long)out_size / scale;
        if (derive(sz, osz, S, B, ID, H)) { ok = true; break; }
    }
    if (!ok) { H = 8; ID = 64; B = 256; S = 64; }
    long dIn = ID + H;

    size_t pre_bytes = (size_t)S * 4 * H * B * sizeof(float);
    float* pre = (ws_size >= pre_bytes) ? (float*)d_ws : g_pre_static;

    k_dtype<<<dim3(13), dim3(256), 0, stream>>>(
        x, Wf, bfv, qf, Wi, biv, qi, Wg, bgv, qg, Wo, bov, qo,
        in_sizes[0], in_sizes[1], in_sizes[2], in_sizes[3],
        in_sizes[4], in_sizes[5], in_sizes[6], in_sizes[7],
        in_sizes[8], in_sizes[9], in_sizes[10], in_sizes[11], in_sizes[12]);

    if (H == 8 && ID == 64) {
        k_pre8<64><<<dim3((unsigned)S, (unsigned)((B + 63) / 64)), dim3(64), 0, stream>>>(
            x, Wf, bfv, Wi, biv, Wg, bgv, Wo, bov, pre, (int)S, (int)B);
    } else {
        int SP = (int)ID + 1;
        size_t lds_bytes = (size_t)(64*SP + 4*H*(dIn + 1) + 4*H) * sizeof(float);
        k_pre_gen<<<dim3((unsigned)S, (unsigned)((B + 63) / 64)), dim3(256), lds_bytes, stream>>>(
            x, Wf, bfv, Wi, biv, Wg, bgv, Wo, bov, pre,
            (int)S, (int)B, (int)ID, (int)H, SP);
    }

    if (H == 8) {
        k_rec8<<<dim3((unsigned)((B + 15) / 16)), dim3(64), 0, stream>>>(
            Wf, qf, Wi, qi, Wg, qg, Wo, qo, pre, out, (int)S, (int)B, (int)ID);
    } else {
        k_rec_g<<<dim3((unsigned)((B + 63) / 64)), dim3(64), 0, stream>>>(
            pre, Wf, qf, Wi, qi, Wg, qg, Wo, qo, out, (int)S, (int)B, (int)ID, (int)H);
    }
}

// Round 9
// 164.640 us; speedup vs baseline: 3.4708x; 1.0931x over previous
//
#include <hip/hip_runtime.h>
#include <hip/hip_bf16.h>

__device__ float g_pre_static[8 * 1024 * 1024];  // fallback scratch (32 MB)

__device__ __forceinline__ float sigm(float x)  { return 1.0f/(1.0f + __expf(-x)); }
__device__ __forceinline__ float tanh_(float x) { float e = __expf(2.0f*x); return (e-1.0f)/(e+1.0f); }

// ---------------------------------------------------------------------------
// Specialized pre-GEMM, H == 8, ID == IDD (compile-time), f32 inputs.
// pre layout: pre[((t*B + b)*4 + g)*8 + w]  (32 consecutive floats per (t,b)).
// grid = (S, ceil(B/64)), block = 64 (one thread per b, all 32 outputs).
template<int IDD>
__global__ __launch_bounds__(64) void k_pre8(
    const float* __restrict__ x_,
    const float* __restrict__ W0, const float* __restrict__ b0p,
    const float* __restrict__ W1, const float* __restrict__ b1p,
    const float* __restrict__ W2, const float* __restrict__ b2p,
    const float* __restrict__ W3, const float* __restrict__ b3p,
    float* __restrict__ pre, int S, int B)
{
    constexpr int DIN = IDD + 8;
    __shared__ float wsh[32 * IDD];   // row gw = g*8+w, col k (broadcast reads)
    __shared__ float sb32[32];
    const int t   = blockIdx.x;
    const int tid = threadIdx.x;
    const long b  = (long)blockIdx.y * 64 + tid;
    const float* Wp[4] = {W0, W1, W2, W3};
    const float* bp[4] = {b0p, b1p, b2p, b3p};

    #pragma unroll
    for (int it = 0; it < (32*IDD)/64; ++it) {
        int idx = it*64 + tid;
        int gw = idx / IDD, k = idx % IDD;
        wsh[idx] = Wp[gw >> 3][(gw & 7)*DIN + k];
    }
    if (tid < 32) sb32[tid] = bp[tid >> 3][tid & 7];
    __syncthreads();

    if (b >= B) return;
    float xr[IDD];
    const float4* xv = (const float4*)(x_ + ((long)t*B + b)*IDD);
    #pragma unroll
    for (int i = 0; i < IDD/4; ++i) {
        float4 v = xv[i];
        xr[4*i] = v.x; xr[4*i+1] = v.y; xr[4*i+2] = v.z; xr[4*i+3] = v.w;
    }

    float acc[32];
    #pragma unroll
    for (int gw = 0; gw < 32; ++gw) {
        float a = sb32[gw];
        const float4* wr = (const float4*)&wsh[gw*IDD];   // LDS broadcast
        #pragma unroll
        for (int k4 = 0; k4 < IDD/4; ++k4) {
            float4 wv = wr[k4];
            a += xr[4*k4]*wv.x + xr[4*k4+1]*wv.y + xr[4*k4+2]*wv.z + xr[4*k4+3]*wv.w;
        }
        acc[gw] = a;
    }
    float4* op = (float4*)(pre + ((long)t*B + b)*32);
    #pragma unroll
    for (int i = 0; i < 8; ++i)
        op[i] = make_float4(acc[4*i], acc[4*i+1], acc[4*i+2], acc[4*i+3]);
}

// ---------------------------------------------------------------------------
// Generic pre-GEMM fallback (runtime ID/H), f32 inputs, same pre layout.
__global__ __launch_bounds__(256) void k_pre_gen(
    const float* __restrict__ x_,
    const float* W0, const float* b0p,
    const float* W1, const float* b1p,
    const float* W2, const float* b2p,
    const float* W3, const float* b3p,
    float* __restrict__ pre,
    int S, int B, int ID, int H, int SP)
{
    extern __shared__ float lds[];
    const int dIn  = ID + H;
    const int dInP = dIn + 1;
    float* xs    = lds;
    float* wsh   = lds + 64*SP;
    float* sbias = wsh + 4*H*dInP;
    const int t   = blockIdx.x;
    const int tid = threadIdx.x;
    const int bl  = tid & 63;
    const int q   = tid >> 6;
    const int b0  = blockIdx.y * 64;
    const float* Wp[4] = {W0, W1, W2, W3};
    const float* bp[4] = {b0p, b1p, b2p, b3p};

    for (int g = 0; g < 4; ++g)
        for (int idx = tid; idx < H*dIn; idx += 256) {
            int w = idx / dIn, k = idx - w*dIn;
            wsh[(g*H + w)*dInP + k] = Wp[g][idx];
        }
    for (int idx = tid; idx < 4*H; idx += 256)
        sbias[idx] = bp[idx / H][idx % H];

    {
        int total = 64 * ID;
        for (int i = tid; i < total; i += 256) {
            int r = i / ID, c = i - r*ID;
            long bb = (long)b0 + r; if (bb >= B) bb = B - 1;
            xs[r*SP + c] = x_[((long)t*B + bb)*ID + c];
        }
    }
    __syncthreads();

    const int b = b0 + bl;
    if (b < B) {
        const float* xrow = &xs[bl*SP];
        float* orow = pre + (((long)t*B + b)*4 + q)*H;
        for (int w = 0; w < H; ++w) {
            float acc = sbias[q*H + w];
            const float* wrow = &wsh[(q*H + w)*dInP];
            for (int k = 0; k < ID; ++k) acc += xrow[k] * wrow[k];
            orow[w] = acc;
        }
    }
}

// ---------------------------------------------------------------------------
// Recurrence, H==8 fast path. Closed-form qgate (validated vs state-vector
// sim in R4):
//   expz[w<7] = cos(q_w) * prod_{j<=w} cos(theta_j)
//   expz[7]   = cos(theta_7 + q_7) * prod_{j<7} cos(theta_j)
// One WAVE = 16 batch elements; lane = g*16 + lb. Weights/q in registers.
// pre flows through a 4-deep register prefetch pipeline; ALL pa/pb indices
// are compile-time (runtime indexing demotes the arrays to LDS scratch —
// measured R8: LDS_Block_Size 4096, 38400 bank conflicts, +8 us).
__global__ __launch_bounds__(64) void k_rec8(
    const float* __restrict__ W0, const float* __restrict__ q0,
    const float* __restrict__ W1, const float* __restrict__ q1,
    const float* __restrict__ W2, const float* __restrict__ q2,
    const float* __restrict__ W3, const float* __restrict__ q3,
    const float* __restrict__ pre,
    float* __restrict__ out, int S, int B, int ID)
{
    const int dIn = ID + 8;
    const int tid = threadIdx.x;
    const int g   = tid >> 4;
    const int lb  = tid & 15;
    const int b   = blockIdx.x * 16 + lb;
    const int bs  = (b < B) ? b : (B - 1);
    const float* Wp[4] = {W0, W1, W2, W3};
    const float* qp[4] = {q0, q1, q2, q3};

    float wh[8][8];
    #pragma unroll
    for (int w = 0; w < 8; ++w)
        #pragma unroll
        for (int j = 0; j < 8; ++j)
            wh[w][j] = Wp[g][(long)w*dIn + ID + j];
    float cq[8];
    #pragma unroll
    for (int w = 0; w < 8; ++w) {
        float qv = qp[g][w];
        cq[w] = (w < 7) ? __cosf(qv) : qv;
    }
    const float ascl = (g == 2) ? 2.0f : 1.0f;   // gate 2: tanh = 2*sigm(2x)-1
    const float aoff = (g == 2) ? -1.0f : 0.0f;

    float hx[8], cx[8];
    #pragma unroll
    for (int w = 0; w < 8; ++w) { hx[w] = 0.0f; cx[w] = 0.0f; }

    const float4* base = (const float4*)(pre + ((long)bs*4 + g)*8);
    const long tstep = (long)B * 8;              // float4 units per t

    float4 pa[4], pb[4];
    #pragma unroll
    for (int d = 0; d < 4; ++d) {
        int tt = (d < S) ? d : (S - 1);
        pa[d] = base[(long)tt*tstep];
        pb[d] = base[(long)tt*tstep + 1];
    }

    auto step = [&](float4 ca, float4 cb, int t) {
        const float pv[8] = {ca.x, ca.y, ca.z, ca.w, cb.x, cb.y, cb.z, cb.w};
        float th[8];
        #pragma unroll
        for (int w = 0; w < 8; ++w) {
            float a = pv[w];
            #pragma unroll
            for (int j = 0; j < 8; ++j) a += wh[w][j]*hx[j];
            th[w] = a;
        }
        float co[8];
        #pragma unroll
        for (int w = 0; w < 7; ++w) co[w] = __cosf(th[w]);
        co[7] = __cosf(th[7] + cq[7]);
        float cum = 1.0f, gt[8];
        #pragma unroll
        for (int w = 0; w < 7; ++w) {
            cum *= co[w];
            gt[w] = cq[w] * cum;
        }
        gt[7] = cum * co[7];
        float act[8];
        #pragma unroll
        for (int w = 0; w < 8; ++w)
            act[w] = ascl * sigm(ascl * gt[w]) + aoff;

        // issue all 32 independent shuffles before any consumer
        float fv[8], iv[8], gv[8], ov[8];
        #pragma unroll
        for (int w = 0; w < 8; ++w) fv[w] = __shfl(act[w], lb,      64);
        #pragma unroll
        for (int w = 0; w < 8; ++w) iv[w] = __shfl(act[w], 16 + lb, 64);
        #pragma unroll
        for (int w = 0; w < 8; ++w) gv[w] = __shfl(act[w], 32 + lb, 64);
        #pragma unroll
        for (int w = 0; w < 8; ++w) ov[w] = __shfl(act[w], 48 + lb, 64);

        #pragma unroll
        for (int w = 0; w < 8; ++w) {
            cx[w] = fv[w]*cx[w] + iv[w]*gv[w];
            hx[w] = ov[w]*tanh_(cx[w]);
        }
        if (b < B) {
            float2 st = make_float2(hx[2*g], hx[2*g + 1]);
            *(float2*)(out + ((long)t*B + b)*8 + 2*g) = st;
        }
    };

    for (int t0 = 0; t0 < S; t0 += 4) {
        #pragma unroll
        for (int d = 0; d < 4; ++d) {       // d compile-time everywhere
            const int t = t0 + d;
            if (t < S) {
                float4 ca = pa[d], cb = pb[d];     // waits on load from t-4
                int tn = t + 4; if (tn >= S) tn = S - 1;
                pa[d] = base[(long)tn*tstep];      // issue t+4, no wait
                pb[d] = base[(long)tn*tstep + 1];
                step(ca, cb, t);
            }
        }
    }

    if (b < B) {
        float2 sh = make_float2(hx[2*g], hx[2*g + 1]);
        float2 sc = make_float2(cx[2*g], cx[2*g + 1]);
        *(float2*)(out + ((long)S*B + b)*8 + 2*g)     = sh;
        *(float2*)(out + ((long)S*B + B + b)*8 + 2*g) = sc;
    }
}

// ---------------------------------------------------------------------------
// Generic runtime-H recurrence fallback (H <= 32), f32, same pre layout.
__global__ __launch_bounds__(64) void k_rec_g(
    const float* __restrict__ pre,
    const float* W0, const float* q0,
    const float* W1, const float* q1,
    const float* W2, const float* q2,
    const float* W3, const float* q3,
    float* __restrict__ out, int S, int B, int ID, int H)
{
    __shared__ float sWh[4*32*32];
    __shared__ float scq[4*32];
    const int dIn = ID + H;
    const int tid = threadIdx.x;
    const int b   = blockIdx.x*64 + tid;
    const float* Wp[4] = {W0, W1, W2, W3};
    const float* qp[4] = {q0, q1, q2, q3};

    for (int idx = tid; idx < 4*H*H; idx += 64) {
        int g = idx / (H*H), r = idx % (H*H);
        int w = r / H, j = r % H;
        sWh[(g*H + w)*H + j] = Wp[g][(long)w*dIn + ID + j];
    }
    for (int idx = tid; idx < 4*H; idx += 64) {
        int g = idx / H, w = idx % H;
        float qv = qp[g][w];
        scq[idx] = (w < H-1) ? __cosf(qv) : qv;
    }
    __syncthreads();
    if (b >= B) return;

    float hx[32], cx[32], gate[4][32], th[32];
    for (int w = 0; w < H; ++w) { hx[w] = 0.0f; cx[w] = 0.0f; }

    for (int t = 0; t < S; ++t) {
        const float* pt = pre + ((long)t*B + b)*4*H;
        for (int g = 0; g < 4; ++g) {
            for (int w = 0; w < H; ++w) {
                float a = pt[g*H + w];
                const float* wr = &sWh[(g*H + w)*H];
                for (int j = 0; j < H; ++j) a += wr[j]*hx[j];
                th[w] = a;
            }
            float cum = 1.0f;
            for (int w = 0; w < H-1; ++w) {
                cum *= __cosf(th[w]);
                gate[g][w] = scq[g*H + w] * cum;
            }
            gate[g][H-1] = cum * __cosf(th[H-1] + scq[g*H + H-1]);
        }
        float* orow = out + ((long)t*B + b)*H;
        for (int w = 0; w < H; ++w) {
            float fv = sigm (gate[0][w]);
            float iv = sigm (gate[1][w]);
            float gv = tanh_(gate[2][w]);
            float ov = sigm (gate[3][w]);
            cx[w] = fv*cx[w] + iv*gv;
            hx[w] = ov*tanh_(cx[w]);
            orow[w] = hx[w];
        }
    }
    float* oh = out + ((long)S*B + b)*H;
    float* oc = out + ((long)S*B + B + b)*H;
    for (int w = 0; w < H; ++w) { oh[w] = hx[w]; oc[w] = cx[w]; }
}

static bool derive(long sz[13], long osz, long& S, long& B, long& ID, long& H) {
    H = sz[3];
    long dIn = (H > 0) ? sz[1] / H : 0;
    ID = dIn - H;
    long TB = (ID > 0) ? sz[0] / ID : 0;
    B = (H > 0) ? (osz / H - TB) / 2 : 0;
    S = (B > 0) ? TB / B : 0;
    return (H >= 1 && H <= 32 && ID >= 1 && B >= 1 && S >= 1 &&
            S*B == TB && (S*B + 2*B)*H == osz &&
            dIn*H == sz[1] && TB*ID == sz[0]);
}

extern "C" void kernel_launch(void* const* d_in, const int* in_sizes, int n_in,
                              void* d_out, int out_size, void* d_ws, size_t ws_size,
                              hipStream_t stream) {
    const float* x  = (const float*)d_in[0];
    const float* Wf = (const float*)d_in[1];  const float* bfv = (const float*)d_in[2];  const float* qf = (const float*)d_in[3];
    const float* Wi = (const float*)d_in[4];  const float* biv = (const float*)d_in[5];  const float* qi = (const float*)d_in[6];
    const float* Wg = (const float*)d_in[7];  const float* bgv = (const float*)d_in[8];  const float* qg = (const float*)d_in[9];
    const float* Wo = (const float*)d_in[10]; const float* bov = (const float*)d_in[11]; const float* qo = (const float*)d_in[12];
    float* out = (float*)d_out;

    long S = 0, B = 0, ID = 0, H = 0;
    bool ok = false;
    for (int scale : {1, 4, 2}) {
        long sz[13];
        for (int i = 0; i < 13; ++i) sz[i] = (long)in_sizes[i] / scale;
        long osz = (long)out_size / scale;
        if (derive(sz, osz, S, B, ID, H)) { ok = true; break; }
    }
    if (!ok) { H = 8; ID = 64; B = 256; S = 64; }
    long dIn = ID + H;

    size_t pre_bytes = (size_t)S * 4 * H * B * sizeof(float);
    float* pre = (ws_size >= pre_bytes) ? (float*)d_ws : g_pre_static;

    if (H == 8 && ID == 64) {
        k_pre8<64><<<dim3((unsigned)S, (unsigned)((B + 63) / 64)), dim3(64), 0, stream>>>(
            x, Wf, bfv, Wi, biv, Wg, bgv, Wo, bov, pre, (int)S, (int)B);
    } else {
        int SP = (int)ID + 1;
        size_t lds_bytes = (size_t)(64*SP + 4*H*(dIn + 1) + 4*H) * sizeof(float);
        k_pre_gen<<<dim3((unsigned)S, (unsigned)((B + 63) / 64)), dim3(256), lds_bytes, stream>>>(
            x, Wf, bfv, Wi, biv, Wg, bgv, Wo, bov, pre,
            (int)S, (int)B, (int)ID, (int)H, SP);
    }

    if (H == 8) {
        k_rec8<<<dim3((unsigned)((B + 15) / 16)), dim3(64), 0, stream>>>(
            Wf, qf, Wi, qi, Wg, qg, Wo, qo, pre, out, (int)S, (int)B, (int)ID);
    } else {
        k_rec_g<<<dim3((unsigned)((B + 63) / 64)), dim3(64), 0, stream>>>(
            pre, Wf, qf, Wi, qi, Wg, qg, Wo, qo, out, (int)S, (int)B, (int)ID, (int)H);
    }
}

// Round 10
// 120.564 us; speedup vs baseline: 4.7397x; 1.3656x over previous
//
#include <hip/hip_runtime.h>
#include <hip/hip_bf16.h>

__device__ float g_pre_static[8 * 1024 * 1024];  // fallback scratch (32 MB)

__device__ __forceinline__ float rcp_(float x)   { return __builtin_amdgcn_rcpf(x); }
__device__ __forceinline__ float sigm_f(float x) { return rcp_(1.0f + __expf(-x)); }
__device__ __forceinline__ float tanh_f(float x) { return 1.0f - 2.0f*rcp_(__expf(2.0f*x) + 1.0f); }
// slow-but-exact versions for the generic fallback
__device__ __forceinline__ float sigm(float x)  { return 1.0f/(1.0f + __expf(-x)); }
__device__ __forceinline__ float tanh_(float x) { float e = __expf(2.0f*x); return (e-1.0f)/(e+1.0f); }

// ---------------------------------------------------------------------------
// Specialized pre-GEMM, H == 8, ID == IDD (compile-time), f32 inputs.
// pre layout: pre[((t*B + b)*4 + g)*8 + w]  (32 consecutive floats per (t,b)).
// grid = (S, ceil(B/64)), block = 64 (one thread per b, all 32 outputs).
template<int IDD>
__global__ __launch_bounds__(64) void k_pre8(
    const float* __restrict__ x_,
    const float* __restrict__ W0, const float* __restrict__ b0p,
    const float* __restrict__ W1, const float* __restrict__ b1p,
    const float* __restrict__ W2, const float* __restrict__ b2p,
    const float* __restrict__ W3, const float* __restrict__ b3p,
    float* __restrict__ pre, int S, int B)
{
    constexpr int DIN = IDD + 8;
    __shared__ float wsh[32 * IDD];   // row gw = g*8+w, col k (broadcast reads)
    __shared__ float sb32[32];
    const int t   = blockIdx.x;
    const int tid = threadIdx.x;
    const long b  = (long)blockIdx.y * 64 + tid;
    const float* Wp[4] = {W0, W1, W2, W3};
    const float* bp[4] = {b0p, b1p, b2p, b3p};

    #pragma unroll
    for (int it = 0; it < (32*IDD)/64; ++it) {
        int idx = it*64 + tid;
        int gw = idx / IDD, k = idx % IDD;
        wsh[idx] = Wp[gw >> 3][(gw & 7)*DIN + k];
    }
    if (tid < 32) sb32[tid] = bp[tid >> 3][tid & 7];
    __syncthreads();

    if (b >= B) return;
    float xr[IDD];
    const float4* xv = (const float4*)(x_ + ((long)t*B + b)*IDD);
    #pragma unroll
    for (int i = 0; i < IDD/4; ++i) {
        float4 v = xv[i];
        xr[4*i] = v.x; xr[4*i+1] = v.y; xr[4*i+2] = v.z; xr[4*i+3] = v.w;
    }

    float acc[32];
    #pragma unroll
    for (int gw = 0; gw < 32; ++gw) {
        float a = sb32[gw];
        const float4* wr = (const float4*)&wsh[gw*IDD];   // LDS broadcast
        #pragma unroll
        for (int k4 = 0; k4 < IDD/4; ++k4) {
            float4 wv = wr[k4];
            a += xr[4*k4]*wv.x + xr[4*k4+1]*wv.y + xr[4*k4+2]*wv.z + xr[4*k4+3]*wv.w;
        }
        acc[gw] = a;
    }
    float4* op = (float4*)(pre + ((long)t*B + b)*32);
    #pragma unroll
    for (int i = 0; i < 8; ++i)
        op[i] = make_float4(acc[4*i], acc[4*i+1], acc[4*i+2], acc[4*i+3]);
}

// ---------------------------------------------------------------------------
// Generic pre-GEMM fallback (runtime ID/H), f32 inputs, same pre layout.
__global__ __launch_bounds__(256) void k_pre_gen(
    const float* __restrict__ x_,
    const float* W0, const float* b0p,
    const float* W1, const float* b1p,
    const float* W2, const float* b2p,
    const float* W3, const float* b3p,
    float* __restrict__ pre,
    int S, int B, int ID, int H, int SP)
{
    extern __shared__ float lds[];
    const int dIn  = ID + H;
    const int dInP = dIn + 1;
    float* xs    = lds;
    float* wsh   = lds + 64*SP;
    float* sbias = wsh + 4*H*dInP;
    const int t   = blockIdx.x;
    const int tid = threadIdx.x;
    const int bl  = tid & 63;
    const int q   = tid >> 6;
    const int b0  = blockIdx.y * 64;
    const float* Wp[4] = {W0, W1, W2, W3};
    const float* bp[4] = {b0p, b1p, b2p, b3p};

    for (int g = 0; g < 4; ++g)
        for (int idx = tid; idx < H*dIn; idx += 256) {
            int w = idx / dIn, k = idx - w*dIn;
            wsh[(g*H + w)*dInP + k] = Wp[g][idx];
        }
    for (int idx = tid; idx < 4*H; idx += 256)
        sbias[idx] = bp[idx / H][idx % H];

    {
        int total = 64 * ID;
        for (int i = tid; i < total; i += 256) {
            int r = i / ID, c = i - r*ID;
            long bb = (long)b0 + r; if (bb >= B) bb = B - 1;
            xs[r*SP + c] = x_[((long)t*B + bb)*ID + c];
        }
    }
    __syncthreads();

    const int b = b0 + bl;
    if (b < B) {
        const float* xrow = &xs[bl*SP];
        float* orow = pre + (((long)t*B + b)*4 + q)*H;
        for (int w = 0; w < H; ++w) {
            float acc = sbias[q*H + w];
            const float* wrow = &wsh[(q*H + w)*dInP];
            for (int k = 0; k < ID; ++k) acc += xrow[k] * wrow[k];
            orow[w] = acc;
        }
    }
}

// ---------------------------------------------------------------------------
// Recurrence, H==8 fast path. Closed-form qgate (validated vs state-vector
// sim in R4), re-expressed per-lane:
//   c_j = cos(theta_j + (j==7 ? q_7 : 0))
//   gate_w = (w<7 ? cos(q_w) : 1) * prod_{j<=w} c_j
// Lane = b2*32 + g*8 + w: one lane per (gate, wire), 2 batch elems per wave.
// All divisions via v_rcp_f32 (R9 post-mortem: 16 exact f32 divides/step were
// the dominant hidden serial cost). 3 single-wait bpermute groups per step.
__global__ __launch_bounds__(64) void k_rec8(
    const float* __restrict__ W0, const float* __restrict__ q0,
    const float* __restrict__ W1, const float* __restrict__ q1,
    const float* __restrict__ W2, const float* __restrict__ q2,
    const float* __restrict__ W3, const float* __restrict__ q3,
    const float* __restrict__ pre,
    float* __restrict__ out, int S, int B, int ID)
{
    const int dIn  = ID + 8;
    const int lane = threadIdx.x;
    const int gw   = lane & 31;
    const int g    = gw >> 3;          // gate 0..3
    const int w    = gw & 7;           // wire 0..7
    const int b    = blockIdx.x*2 + (lane >> 5);
    const int bs   = (b < B) ? b : (B - 1);
    const float* Wp[4] = {W0, W1, W2, W3};
    const float* qp[4] = {q0, q1, q2, q3};

    // my (g,w) hidden-weight row + q constants, in registers
    float wr[8];
    #pragma unroll
    for (int j = 0; j < 8; ++j) wr[j] = Wp[g][(long)w*dIn + ID + j];
    const float qv   = qp[g][w];
    const float mult = (w < 7) ? __cosf(qv) : 1.0f;
    const float qadd = (w == 7) ? qv : 0.0f;
    const float ascl = (g == 2) ? 2.0f : 1.0f;   // gate 2: tanh = 2*sigm(2x)-1
    const float aoff = (g == 2) ? -1.0f : 0.0f;

    // shfl source lanes (precomputed)
    int oct = lane & 56;               // my (b2,g) octet base
    int srcw[8];
    #pragma unroll
    for (int j = 0; j < 8; ++j) srcw[j] = oct | j;       // wire j, my octet
    int srcg[4];
    #pragma unroll
    for (int G = 0; G < 4; ++G) srcg[G] = (lane & 32) | (G << 3) | w;

    float cxw = 0.0f, hxw = 0.0f;
    float hxj[8];
    #pragma unroll
    for (int j = 0; j < 8; ++j) hxj[j] = 0.0f;

    const float* base = pre + (long)bs*32 + gw;   // lane-coalesced
    const long  tstep = (long)B*32;

    float pf[4];
    #pragma unroll
    for (int d = 0; d < 4; ++d) {
        int tt = (d < S) ? d : (S - 1);
        pf[d] = base[(long)tt*tstep];
    }

    for (int t0 = 0; t0 < S; t0 += 4) {
        #pragma unroll
        for (int d = 0; d < 4; ++d) {          // d compile-time everywhere
            const int t = t0 + d;
            if (t < S) {
                float pcur = pf[d];            // waits on load from t-4
                int tn = t + 4; if (tn >= S) tn = S - 1;
                pf[d] = base[(long)tn*tstep];  // issue t+4, no wait

                float th = pcur;
                #pragma unroll
                for (int j = 0; j < 8; ++j) th = fmaf(wr[j], hxj[j], th);
                float c = __cosf(th + qadd);

                // gather all 8 cos of my octet (8 independent bpermutes, 1 wait)
                float cj[8];
                #pragma unroll
                for (int j = 0; j < 8; ++j) cj[j] = __shfl(c, srcw[j], 64);
                float P = cj[0];
                #pragma unroll
                for (int j = 1; j < 8; ++j) P *= (j <= w) ? cj[j] : 1.0f;

                float act = ascl * sigm_f(ascl * (mult * P)) + aoff;

                // gather the 4 gate activations for my wire (1 wait)
                float fv = __shfl(act, srcg[0], 64);
                float iv = __shfl(act, srcg[1], 64);
                float gv = __shfl(act, srcg[2], 64);
                float ov = __shfl(act, srcg[3], 64);

                cxw = fv*cxw + iv*gv;
                hxw = ov * tanh_f(cxw);

                if (g == 0 && b < B) out[((long)t*B + b)*8 + w] = hxw;

                // gather hx vector for next step's theta (1 wait)
                #pragma unroll
                for (int j = 0; j < 8; ++j) hxj[j] = __shfl(hxw, srcw[j], 64);
            }
        }
    }

    if (g == 0 && b < B) {
        out[((long)S*B + b)*8 + w]     = hxw;
        out[((long)S*B + B + b)*8 + w] = cxw;
    }
}

// ---------------------------------------------------------------------------
// Generic runtime-H recurrence fallback (H <= 32), f32, same pre layout.
__global__ __launch_bounds__(64) void k_rec_g(
    const float* __restrict__ pre,
    const float* W0, const float* q0,
    const float* W1, const float* q1,
    const float* W2, const float* q2,
    const float* W3, const float* q3,
    float* __restrict__ out, int S, int B, int ID, int H)
{
    __shared__ float sWh[4*32*32];
    __shared__ float scq[4*32];
    const int dIn = ID + H;
    const int tid = threadIdx.x;
    const int b   = blockIdx.x*64 + tid;
    const float* Wp[4] = {W0, W1, W2, W3};
    const float* qp[4] = {q0, q1, q2, q3};

    for (int idx = tid; idx < 4*H*H; idx += 64) {
        int g = idx / (H*H), r = idx % (H*H);
        int w = r / H, j = r % H;
        sWh[(g*H + w)*H + j] = Wp[g][(long)w*dIn + ID + j];
    }
    for (int idx = tid; idx < 4*H; idx += 64) {
        int g = idx / H, w = idx % H;
        float qv = qp[g][w];
        scq[idx] = (w < H-1) ? __cosf(qv) : qv;
    }
    __syncthreads();
    if (b >= B) return;

    float hx[32], cx[32], gate[4][32], th[32];
    for (int w = 0; w < H; ++w) { hx[w] = 0.0f; cx[w] = 0.0f; }

    for (int t = 0; t < S; ++t) {
        const float* pt = pre + ((long)t*B + b)*4*H;
        for (int g = 0; g < 4; ++g) {
            for (int w = 0; w < H; ++w) {
                float a = pt[g*H + w];
                const float* wrp = &sWh[(g*H + w)*H];
                for (int j = 0; j < H; ++j) a += wrp[j]*hx[j];
                th[w] = a;
            }
            float cum = 1.0f;
            for (int w = 0; w < H-1; ++w) {
                cum *= __cosf(th[w]);
                gate[g][w] = scq[g*H + w] * cum;
            }
            gate[g][H-1] = cum * __cosf(th[H-1] + scq[g*H + H-1]);
        }
        float* orow = out + ((long)t*B + b)*H;
        for (int w = 0; w < H; ++w) {
            float fv = sigm (gate[0][w]);
            float iv = sigm (gate[1][w]);
            float gv = tanh_(gate[2][w]);
            float ov = sigm (gate[3][w]);
            cx[w] = fv*cx[w] + iv*gv;
            hx[w] = ov*tanh_(cx[w]);
            orow[w] = hx[w];
        }
    }
    float* oh = out + ((long)S*B + b)*H;
    float* oc = out + ((long)S*B + B + b)*H;
    for (int w = 0; w < H; ++w) { oh[w] = hx[w]; oc[w] = cx[w]; }
}

static bool derive(long sz[13], long osz, long& S, long& B, long& ID, long& H) {
    H = sz[3];
    long dIn = (H > 0) ? sz[1] / H : 0;
    ID = dIn - H;
    long TB = (ID > 0) ? sz[0] / ID : 0;
    B = (H > 0) ? (osz / H - TB) / 2 : 0;
    S = (B > 0) ? TB / B : 0;
    return (H >= 1 && H <= 32 && ID >= 1 && B >= 1 && S >= 1 &&
            S*B == TB && (S*B + 2*B)*H == osz &&
            dIn*H == sz[1] && TB*ID == sz[0]);
}

extern "C" void kernel_launch(void* const* d_in, const int* in_sizes, int n_in,
                              void* d_out, int out_size, void* d_ws, size_t ws_size,
                              hipStream_t stream) {
    const float* x  = (const float*)d_in[0];
    const float* Wf = (const float*)d_in[1];  const float* bfv = (const float*)d_in[2];  const float* qf = (const float*)d_in[3];
    const float* Wi = (const float*)d_in[4];  const float* biv = (const float*)d_in[5];  const float* qi = (const float*)d_in[6];
    const float* Wg = (const float*)d_in[7];  const float* bgv = (const float*)d_in[8];  const float* qg = (const float*)d_in[9];
    const float* Wo = (const float*)d_in[10]; const float* bov = (const float*)d_in[11]; const float* qo = (const float*)d_in[12];
    float* out = (float*)d_out;

    long S = 0, B = 0, ID = 0, H = 0;
    bool ok = false;
    for (int scale : {1, 4, 2}) {
        long sz[13];
        for (int i = 0; i < 13; ++i) sz[i] = (long)in_sizes[i] / scale;
        long osz = (long)out_size / scale;
        if (derive(sz, osz, S, B, ID, H)) { ok = true; break; }
    }
    if (!ok) { H = 8; ID = 64; B = 256; S = 64; }
    long dIn = ID + H;

    size_t pre_bytes = (size_t)S * 4 * H * B * sizeof(float);
    float* pre = (ws_size >= pre_bytes) ? (float*)d_ws : g_pre_static;

    if (H == 8 && ID == 64) {
        k_pre8<64><<<dim3((unsigned)S, (unsigned)((B + 63) / 64)), dim3(64), 0, stream>>>(
            x, Wf, bfv, Wi, biv, Wg, bgv, Wo, bov, pre, (int)S, (int)B);
    } else {
        int SP = (int)ID + 1;
        size_t lds_bytes = (size_t)(64*SP + 4*H*(dIn + 1) + 4*H) * sizeof(float);
        k_pre_gen<<<dim3((unsigned)S, (unsigned)((B + 63) / 64)), dim3(256), lds_bytes, stream>>>(
            x, Wf, bfv, Wi, biv, Wg, bgv, Wo, bov, pre,
            (int)S, (int)B, (int)ID, (int)H, SP);
    }

    if (H == 8) {
        k_rec8<<<dim3((unsigned)((B + 1) / 2)), dim3(64), 0, stream>>>(
            Wf, qf, Wi, qi, Wg, qg, Wo, qo, pre, out, (int)S, (int)B, (int)ID);
    } else {
        k_rec_g<<<dim3((unsigned)((B + 63) / 64)), dim3(64), 0, stream>>>(
            pre, Wf, qf, Wi, qi, Wg, qg, Wo, qo, out, (int)S, (int)B, (int)ID, (int)H);
    }
}

// Round 12
// 111.786 us; speedup vs baseline: 5.1119x; 1.0785x over previous
//
#include <hip/hip_runtime.h>
#include <hip/hip_bf16.h>

__device__ float g_pre_static[8 * 1024 * 1024];  // fallback scratch (32 MB)

__device__ __forceinline__ float rcp_(float x)   { return __builtin_amdgcn_rcpf(x); }
__device__ __forceinline__ float sigm_f(float x) { return rcp_(1.0f + __expf(-x)); }
__device__ __forceinline__ float tanh_f(float x) { return 1.0f - 2.0f*rcp_(__expf(2.0f*x) + 1.0f); }
__device__ __forceinline__ float sigm(float x)  { return 1.0f/(1.0f + __expf(-x)); }
__device__ __forceinline__ float tanh_(float x) { float e = __expf(2.0f*x); return (e-1.0f)/(e+1.0f); }

// DPP move within 16-lane rows: pure VALU, no lgkmcnt wait (vs ds_bpermute).
// SEMANTICS (verified R11 post-mortem): row_shr:k / row_ror:k deliver to lane
// i the value from lane i-k (mod 16 for ror) — data moves toward HIGHER lanes.
template<int CTRL>
__device__ __forceinline__ float dppf(float x) {
    return __int_as_float(__builtin_amdgcn_update_dpp(
        0, __float_as_int(x), CTRL, 0xF, 0xF, true));
}
// CTRL: row_shr:k = 0x110+k ; row_ror:k = 0x120+k

// ---------------------------------------------------------------------------
// Specialized pre-GEMM, H == 8, ID == IDD (compile-time), f32 inputs.
// pre layout (gate-pair interleaved for the DPP recurrence):
//   pre[(t*B + b)*32 + gp*16 + w*2 + e]   where gate g = 2*gp + e.
// grid = (S, ceil(B/64)), block = 64 (one thread per b, all 32 outputs).
template<int IDD>
__global__ __launch_bounds__(64) void k_pre8(
    const float* __restrict__ x_,
    const float* __restrict__ W0, const float* __restrict__ b0p,
    const float* __restrict__ W1, const float* __restrict__ b1p,
    const float* __restrict__ W2, const float* __restrict__ b2p,
    const float* __restrict__ W3, const float* __restrict__ b3p,
    float* __restrict__ pre, int S, int B)
{
    constexpr int DIN = IDD + 8;
    __shared__ float wsh[32 * IDD];   // row gw = g*8+w, col k (broadcast reads)
    __shared__ float sb32[32];
    const int t   = blockIdx.x;
    const int tid = threadIdx.x;
    const long b  = (long)blockIdx.y * 64 + tid;
    const float* Wp[4] = {W0, W1, W2, W3};
    const float* bp[4] = {b0p, b1p, b2p, b3p};

    #pragma unroll
    for (int it = 0; it < (32*IDD)/64; ++it) {
        int idx = it*64 + tid;
        int gw = idx / IDD, k = idx % IDD;
        wsh[idx] = Wp[gw >> 3][(gw & 7)*DIN + k];
    }
    if (tid < 32) sb32[tid] = bp[tid >> 3][tid & 7];
    __syncthreads();

    if (b >= B) return;
    float xr[IDD];
    const float4* xv = (const float4*)(x_ + ((long)t*B + b)*IDD);
    #pragma unroll
    for (int i = 0; i < IDD/4; ++i) {
        float4 v = xv[i];
        xr[4*i] = v.x; xr[4*i+1] = v.y; xr[4*i+2] = v.z; xr[4*i+3] = v.w;
    }

    float acc[32];
    #pragma unroll
    for (int gw = 0; gw < 32; ++gw) {
        float a = sb32[gw];
        const float4* wr = (const float4*)&wsh[gw*IDD];   // LDS broadcast
        #pragma unroll
        for (int k4 = 0; k4 < IDD/4; ++k4) {
            float4 wv = wr[k4];
            a += xr[4*k4]*wv.x + xr[4*k4+1]*wv.y + xr[4*k4+2]*wv.z + xr[4*k4+3]*wv.w;
        }
        acc[gw] = a;
    }
    // reorder to gate-pair-interleaved layout; all indices compile-time
    float4* op = (float4*)(pre + ((long)t*B + b)*32);
    #pragma unroll
    for (int i = 0; i < 8; ++i) {
        #define SRC(o) (((((o) >> 4)*2 + ((o) & 1))*8) + ((((o) & 15)) >> 1))
        op[i] = make_float4(acc[SRC(4*i)], acc[SRC(4*i+1)],
                            acc[SRC(4*i+2)], acc[SRC(4*i+3)]);
        #undef SRC
    }
}

// ---------------------------------------------------------------------------
// Generic pre-GEMM fallback (runtime ID/H), f32 inputs, OLD layout
// pre[((t*B+b)*4+g)*H + w] — paired only with k_rec_g.
__global__ __launch_bounds__(256) void k_pre_gen(
    const float* __restrict__ x_,
    const float* W0, const float* b0p,
    const float* W1, const float* b1p,
    const float* W2, const float* b2p,
    const float* W3, const float* b3p,
    float* __restrict__ pre,
    int S, int B, int ID, int H, int SP)
{
    extern __shared__ float lds[];
    const int dIn  = ID + H;
    const int dInP = dIn + 1;
    float* xs    = lds;
    float* wsh   = lds + 64*SP;
    float* sbias = wsh + 4*H*dInP;
    const int t   = blockIdx.x;
    const int tid = threadIdx.x;
    const int bl  = tid & 63;
    const int q   = tid >> 6;
    const int b0  = blockIdx.y * 64;
    const float* Wp[4] = {W0, W1, W2, W3};
    const float* bp[4] = {b0p, b1p, b2p, b3p};

    for (int g = 0; g < 4; ++g)
        for (int idx = tid; idx < H*dIn; idx += 256) {
            int w = idx / dIn, k = idx - w*dIn;
            wsh[(g*H + w)*dInP + k] = Wp[g][idx];
        }
    for (int idx = tid; idx < 4*H; idx += 256)
        sbias[idx] = bp[idx / H][idx % H];

    {
        int total = 64 * ID;
        for (int i = tid; i < total; i += 256) {
            int r = i / ID, c = i - r*ID;
            long bb = (long)b0 + r; if (bb >= B) bb = B - 1;
            xs[r*SP + c] = x_[((long)t*B + bb)*ID + c];
        }
    }
    __syncthreads();

    const int b = b0 + bl;
    if (b < B) {
        const float* xrow = &xs[bl*SP];
        float* orow = pre + (((long)t*B + b)*4 + q)*H;
        for (int w = 0; w < H; ++w) {
            float acc = sbias[q*H + w];
            const float* wrow = &wsh[(q*H + w)*dInP];
            for (int k = 0; k < ID; ++k) acc += xrow[k] * wrow[k];
            orow[w] = acc;
        }
    }
}

// ---------------------------------------------------------------------------
// Recurrence, H==8/ID==64 fast path. Closed-form qgate (validated vs
// state-vector sim in R4):
//   gate_w = (w<7 ? cos(q_w) : 1) * prod_{j<=w} cos(theta_j + (j==7?q_7:0))
// Lane = b4*16 + gp*8 + w: one 16-lane DPP row per batch element; each lane
// owns gates {2gp, 2gp+1} of wire w. ALL cross-lane traffic is DPP:
//   prefix product  -> row_shr:1/2/4 scan (lane i <- lane i-k)
//   gate exchange   -> row_ror:8 (octet swap; -8 == +8 mod 16)
//   hx all-gather   -> row_ror:k gives hx_{(w-k)&7}; weights pre-rotated to
//                      wrot[k] = W[w][(w-k)&7]  (R11 bug: used (w+k)&7)
__global__ __launch_bounds__(64) void k_rec8(
    const float* __restrict__ W0, const float* __restrict__ q0,
    const float* __restrict__ W1, const float* __restrict__ q1,
    const float* __restrict__ W2, const float* __restrict__ q2,
    const float* __restrict__ W3, const float* __restrict__ q3,
    const float* __restrict__ pre,
    float* __restrict__ out, int S, int B, int ID)
{
    const int dIn  = ID + 8;
    const int lane = threadIdx.x;
    const int w    = lane & 7;
    const int gp   = (lane >> 3) & 1;
    const int b    = blockIdx.x*4 + (lane >> 4);
    const int bs   = (b < B) ? b : (B - 1);
    const float* Wp[4] = {W0, W1, W2, W3};
    const float* qp[4] = {q0, q1, q2, q3};
    const int g0 = 2*gp, g1 = 2*gp + 1;

    // rotated hidden-weight rows matching ror:k's hx_{(w-k)&7}
    float wrot0[8], wrot1[8];
    #pragma unroll
    for (int k = 0; k < 8; ++k) {
        int j = (w - k) & 7;                   // <-- the R11 fix
        wrot0[k] = Wp[g0][(long)w*dIn + ID + j];
        wrot1[k] = Wp[g1][(long)w*dIn + ID + j];
    }
    const float qv0 = qp[g0][w], qv1 = qp[g1][w];
    const float mult0 = (w < 7) ? __cosf(qv0) : 1.0f;
    const float mult1 = (w < 7) ? __cosf(qv1) : 1.0f;
    const float qadd0 = (w == 7) ? qv0 : 0.0f;
    const float qadd1 = (w == 7) ? qv1 : 0.0f;
    // gate g0==2 (gp=1) uses tanh = 2*sigm(2x)-1; g1 in {1,3} always sigm
    const float ascl = gp ? 2.0f : 1.0f;
    const float aoff = gp ? -1.0f : 0.0f;

    float cxw = 0.0f, hxw = 0.0f;
    float hxr[8];
    #pragma unroll
    for (int k = 0; k < 8; ++k) hxr[k] = 0.0f;

    // per-lane float2: gates (2gp, 2gp+1) of wire w
    const float2* base = (const float2*)(pre + (long)bs*32 + gp*16 + 2*w);
    const long tstep = (long)B*16;   // float2 units per t

    float2 pf[4];
    #pragma unroll
    for (int d = 0; d < 4; ++d) {
        int tt = (d < S) ? d : (S - 1);
        pf[d] = base[(long)tt*tstep];
    }

    for (int t0 = 0; t0 < S; t0 += 4) {
        #pragma unroll
        for (int d = 0; d < 4; ++d) {          // d compile-time everywhere
            const int t = t0 + d;
            if (t < S) {
                float2 pc = pf[d];             // waits on load from t-4
                int tn = t + 4; if (tn >= S) tn = S - 1;
                pf[d] = base[(long)tn*tstep];  // issue t+4, no wait

                float th0 = pc.x, th1 = pc.y;
                #pragma unroll
                for (int k = 0; k < 8; ++k) {
                    th0 = fmaf(wrot0[k], hxr[k], th0);
                    th1 = fmaf(wrot1[k], hxr[k], th1);
                }
                float P0 = __cosf(th0 + qadd0);
                float P1 = __cosf(th1 + qadd1);

                // inclusive prefix product over the 8 wires (DPP scan)
                float s;
                s = dppf<0x111>(P0); P0 *= (w >= 1) ? s : 1.0f;
                s = dppf<0x111>(P1); P1 *= (w >= 1) ? s : 1.0f;
                s = dppf<0x112>(P0); P0 *= (w >= 2) ? s : 1.0f;
                s = dppf<0x112>(P1); P1 *= (w >= 2) ? s : 1.0f;
                s = dppf<0x114>(P0); P0 *= (w >= 4) ? s : 1.0f;
                s = dppf<0x114>(P1); P1 *= (w >= 4) ? s : 1.0f;

                float act0 = ascl * sigm_f(ascl * (mult0 * P0)) + aoff;
                float act1 = sigm_f(mult1 * P1);

                // swap gate-pairs across octets (same wire): row_ror:8
                float ex0 = dppf<0x128>(act0);
                float ex1 = dppf<0x128>(act1);
                float fv = gp ? ex0  : act0;
                float iv = gp ? ex1  : act1;
                float gv = gp ? act0 : ex0;
                float ov = gp ? act1 : ex1;

                cxw = fv*cxw + iv*gv;
                hxw = ov * tanh_f(cxw);

                if (gp == 0 && b < B) out[((long)t*B + b)*8 + w] = hxw;

                // hx all-gather: hxr[k] = hx_{(w-k)&7} via row_ror:k
                // (both octets hold identical hx, so mod-16 wrap is benign)
                hxr[0] = hxw;
                hxr[1] = dppf<0x121>(hxw);
                hxr[2] = dppf<0x122>(hxw);
                hxr[3] = dppf<0x123>(hxw);
                hxr[4] = dppf<0x124>(hxw);
                hxr[5] = dppf<0x125>(hxw);
                hxr[6] = dppf<0x126>(hxw);
                hxr[7] = dppf<0x127>(hxw);
            }
        }
    }

    if (gp == 0 && b < B) {
        out[((long)S*B + b)*8 + w]     = hxw;
        out[((long)S*B + B + b)*8 + w] = cxw;
    }
}

// ---------------------------------------------------------------------------
// Generic runtime-H recurrence fallback (H <= 32), f32, OLD pre layout.
__global__ __launch_bounds__(64) void k_rec_g(
    const float* __restrict__ pre,
    const float* W0, const float* q0,
    const float* W1, const float* q1,
    const float* W2, const float* q2,
    const float* W3, const float* q3,
    float* __restrict__ out, int S, int B, int ID, int H)
{
    __shared__ float sWh[4*32*32];
    __shared__ float scq[4*32];
    const int dIn = ID + H;
    const int tid = threadIdx.x;
    const int b   = blockIdx.x*64 + tid;
    const float* Wp[4] = {W0, W1, W2, W3};
    const float* qp[4] = {q0, q1, q2, q3};

    for (int idx = tid; idx < 4*H*H; idx += 64) {
        int g = idx / (H*H), r = idx % (H*H);
        int w = r / H, j = r % H;
        sWh[(g*H + w)*H + j] = Wp[g][(long)w*dIn + ID + j];
    }
    for (int idx = tid; idx < 4*H; idx += 64) {
        int g = idx / H, w = idx % H;
        float qv = qp[g][w];
        scq[idx] = (w < H-1) ? __cosf(qv) : qv;
    }
    __syncthreads();
    if (b >= B) return;

    float hx[32], cx[32], gate[4][32], th[32];
    for (int w = 0; w < H; ++w) { hx[w] = 0.0f; cx[w] = 0.0f; }

    for (int t = 0; t < S; ++t) {
        const float* pt = pre + ((long)t*B + b)*4*H;
        for (int g = 0; g < 4; ++g) {
            for (int w = 0; w < H; ++w) {
                float a = pt[g*H + w];
                const float* wrp = &sWh[(g*H + w)*H];
                for (int j = 0; j < H; ++j) a += wrp[j]*hx[j];
                th[w] = a;
            }
            float cum = 1.0f;
            for (int w = 0; w < H-1; ++w) {
                cum *= __cosf(th[w]);
                gate[g][w] = scq[g*H + w] * cum;
            }
            gate[g][H-1] = cum * __cosf(th[H-1] + scq[g*H + H-1]);
        }
        float* orow = out + ((long)t*B + b)*H;
        for (int w = 0; w < H; ++w) {
            float fv = sigm (gate[0][w]);
            float iv = sigm (gate[1][w]);
            float gv = tanh_(gate[2][w]);
            float ov = sigm (gate[3][w]);
            cx[w] = fv*cx[w] + iv*gv;
            hx[w] = ov*tanh_(cx[w]);
            orow[w] = hx[w];
        }
    }
    float* oh = out + ((long)S*B + b)*H;
    float* oc = out + ((long)S*B + B + b)*H;
    for (int w = 0; w < H; ++w) { oh[w] = hx[w]; oc[w] = cx[w]; }
}

static bool derive(long sz[13], long osz, long& S, long& B, long& ID, long& H) {
    H = sz[3];
    long dIn = (H > 0) ? sz[1] / H : 0;
    ID = dIn - H;
    long TB = (ID > 0) ? sz[0] / ID : 0;
    B = (H > 0) ? (osz / H - TB) / 2 : 0;
    S = (B > 0) ? TB / B : 0;
    return (H >= 1 && H <= 32 && ID >= 1 && B >= 1 && S >= 1 &&
            S*B == TB && (S*B + 2*B)*H == osz &&
            dIn*H == sz[1] && TB*ID == sz[0]);
}

extern "C" void kernel_launch(void* const* d_in, const int* in_sizes, int n_in,
                              void* d_out, int out_size, void* d_ws, size_t ws_size,
                              hipStream_t stream) {
    const float* x  = (const float*)d_in[0];
    const float* Wf = (const float*)d_in[1];  const float* bfv = (const float*)d_in[2];  const float* qf = (const float*)d_in[3];
    const float* Wi = (const float*)d_in[4];  const float* biv = (const float*)d_in[5];  const float* qi = (const float*)d_in[6];
    const float* Wg = (const float*)d_in[7];  const float* bgv = (const float*)d_in[8];  const float* qg = (const float*)d_in[9];
    const float* Wo = (const float*)d_in[10]; const float* bov = (const float*)d_in[11]; const float* qo = (const float*)d_in[12];
    float* out = (float*)d_out;

    long S = 0, B = 0, ID = 0, H = 0;
    bool ok = false;
    for (int scale : {1, 4, 2}) {
        long sz[13];
        for (int i = 0; i < 13; ++i) sz[i] = (long)in_sizes[i] / scale;
        long osz = (long)out_size / scale;
        if (derive(sz, osz, S, B, ID, H)) { ok = true; break; }
    }
    if (!ok) { H = 8; ID = 64; B = 256; S = 64; }
    long dIn = ID + H;

    size_t pre_bytes = (size_t)S * 4 * H * B * sizeof(float);
    float* pre = (ws_size >= pre_bytes) ? (float*)d_ws : g_pre_static;

    if (H == 8 && ID == 64) {
        k_pre8<64><<<dim3((unsigned)S, (unsigned)((B + 63) / 64)), dim3(64), 0, stream>>>(
            x, Wf, bfv, Wi, biv, Wg, bgv, Wo, bov, pre, (int)S, (int)B);
        k_rec8<<<dim3((unsigned)((B + 3) / 4)), dim3(64), 0, stream>>>(
            Wf, qf, Wi, qi, Wg, qg, Wo, qo, pre, out, (int)S, (int)B, (int)ID);
    } else {
        int SP = (int)ID + 1;
        size_t lds_bytes = (size_t)(64*SP + 4*H*(dIn + 1) + 4*H) * sizeof(float);
        k_pre_gen<<<dim3((unsigned)S, (unsigned)((B + 63) / 64)), dim3(256), lds_bytes, stream>>>(
            x, Wf, bfv, Wi, biv, Wg, bgv, Wo, bov, pre,
            (int)S, (int)B, (int)ID, (int)H, SP);
        k_rec_g<<<dim3((unsigned)((B + 63) / 64)), dim3(64), 0, stream>>>(
            pre, Wf, qf, Wi, qi, Wg, qg, Wo, qo, out, (int)S, (int)B, (int)ID, (int)H);
    }
}

// Round 13
// 102.767 us; speedup vs baseline: 5.5605x; 1.0878x over previous
//
#include <hip/hip_runtime.h>
#include <hip/hip_bf16.h>

__device__ float g_pre_static[8 * 1024 * 1024];  // fallback scratch (32 MB)

__device__ __forceinline__ float rcp_(float x)   { return __builtin_amdgcn_rcpf(x); }
__device__ __forceinline__ float sigm_f(float x) { return rcp_(1.0f + __expf(-x)); }
__device__ __forceinline__ float tanh_f(float x) { return 1.0f - 2.0f*rcp_(__expf(2.0f*x) + 1.0f); }
__device__ __forceinline__ float sigm(float x)  { return 1.0f/(1.0f + __expf(-x)); }
__device__ __forceinline__ float tanh_(float x) { float e = __expf(2.0f*x); return (e-1.0f)/(e+1.0f); }

// DPP move within 16-lane rows: pure VALU, no lgkmcnt wait (vs ds_bpermute).
// SEMANTICS (verified R11/R12): row_shr:k / row_ror:k deliver to lane i the
// value from lane i-k (mod 16 for ror) — data moves toward HIGHER lanes.
template<int CTRL>
__device__ __forceinline__ float dppf(float x) {
    return __int_as_float(__builtin_amdgcn_update_dpp(
        0, __float_as_int(x), CTRL, 0xF, 0xF, true));
}
// CTRL: row_shr:k = 0x110+k ; row_ror:k = 0x120+k

// ---------------------------------------------------------------------------
// Specialized pre-GEMM, H == 8, ID == IDD (compile-time), f32 inputs.
// pre layout (gate-pair interleaved for the DPP recurrence):
//   pre[(t*B + b)*32 + l],  l = gp*16 + w*2 + e,  gate g = 2*gp + e.
// grid = (S, ceil(B/8)), block = 256: thread = bl*32 + l (bl = local batch).
// One thread per output element: W row in REGISTERS (16 L1-hit float4 loads,
// 8-way redundant across bl — avoids LDS row-stride bank conflicts), x row
// via LDS broadcast (one address per 32-lane half-row: conflict-free).
template<int IDD>
__global__ __launch_bounds__(256) void k_pre8(
    const float* __restrict__ x_,
    const float* __restrict__ W0, const float* __restrict__ b0p,
    const float* __restrict__ W1, const float* __restrict__ b1p,
    const float* __restrict__ W2, const float* __restrict__ b2p,
    const float* __restrict__ W3, const float* __restrict__ b3p,
    float* __restrict__ pre, int S, int B)
{
    constexpr int DIN = IDD + 8;
    __shared__ float xs[8][IDD];
    const int t   = blockIdx.x;
    const int tid = threadIdx.x;
    const int bl  = tid >> 5;            // 0..7 local batch
    const int l   = tid & 31;            // interleaved output offset
    const int gp  = l >> 4, w = (l >> 1) & 7, e = l & 1;
    const int g   = 2*gp + e;
    const long b0 = (long)blockIdx.y * 8;
    const float* Wp[4] = {W0, W1, W2, W3};
    const float* bp[4] = {b0p, b1p, b2p, b3p};

    // stage x: 8 rows of IDD floats (128 float4 loads, first 128 threads)
    if (tid < 8*(IDD/4)) {
        int r = tid / (IDD/4), k4 = tid % (IDD/4);
        long bb = b0 + r; if (bb >= B) bb = B - 1;
        float4 v = ((const float4*)(x_ + ((long)t*B + bb)*IDD))[k4];
        ((float4*)&xs[r][0])[k4] = v;
    }

    // my W row into registers (L1-hit after first block on this CU)
    float wr[IDD];
    {
        const float4* wv = (const float4*)(Wp[g] + (long)w*DIN);
        #pragma unroll
        for (int k4 = 0; k4 < IDD/4; ++k4) {
            float4 v = wv[k4];
            wr[4*k4] = v.x; wr[4*k4+1] = v.y; wr[4*k4+2] = v.z; wr[4*k4+3] = v.w;
        }
    }
    float a = bp[g][w];
    __syncthreads();

    const long b = b0 + bl;
    if (b >= B) return;
    const float4* xv = (const float4*)&xs[bl][0];
    #pragma unroll
    for (int k4 = 0; k4 < IDD/4; ++k4) {
        float4 v = xv[k4];                 // broadcast within half-row
        a += wr[4*k4]*v.x + wr[4*k4+1]*v.y + wr[4*k4+2]*v.z + wr[4*k4+3]*v.w;
    }
    pre[((long)t*B + b)*32 + l] = a;       // fully coalesced
}

// ---------------------------------------------------------------------------
// Generic pre-GEMM fallback (runtime ID/H), f32 inputs, OLD layout
// pre[((t*B+b)*4+g)*H + w] — paired only with k_rec_g.
__global__ __launch_bounds__(256) void k_pre_gen(
    const float* __restrict__ x_,
    const float* W0, const float* b0p,
    const float* W1, const float* b1p,
    const float* W2, const float* b2p,
    const float* W3, const float* b3p,
    float* __restrict__ pre,
    int S, int B, int ID, int H, int SP)
{
    extern __shared__ float lds[];
    const int dIn  = ID + H;
    const int dInP = dIn + 1;
    float* xs    = lds;
    float* wsh   = lds + 64*SP;
    float* sbias = wsh + 4*H*dInP;
    const int t   = blockIdx.x;
    const int tid = threadIdx.x;
    const int bl  = tid & 63;
    const int q   = tid >> 6;
    const int b0  = blockIdx.y * 64;
    const float* Wp[4] = {W0, W1, W2, W3};
    const float* bp[4] = {b0p, b1p, b2p, b3p};

    for (int g = 0; g < 4; ++g)
        for (int idx = tid; idx < H*dIn; idx += 256) {
            int w = idx / dIn, k = idx - w*dIn;
            wsh[(g*H + w)*dInP + k] = Wp[g][idx];
        }
    for (int idx = tid; idx < 4*H; idx += 256)
        sbias[idx] = bp[idx / H][idx % H];

    {
        int total = 64 * ID;
        for (int i = tid; i < total; i += 256) {
            int r = i / ID, c = i - r*ID;
            long bb = (long)b0 + r; if (bb >= B) bb = B - 1;
            xs[r*SP + c] = x_[((long)t*B + bb)*ID + c];
        }
    }
    __syncthreads();

    const int b = b0 + bl;
    if (b < B) {
        const float* xrow = &xs[bl*SP];
        float* orow = pre + (((long)t*B + b)*4 + q)*H;
        for (int w = 0; w < H; ++w) {
            float acc = sbias[q*H + w];
            const float* wrow = &wsh[(q*H + w)*dInP];
            for (int k = 0; k < ID; ++k) acc += xrow[k] * wrow[k];
            orow[w] = acc;
        }
    }
}

// ---------------------------------------------------------------------------
// Recurrence, H==8/ID==64 fast path (UNCHANGED from R12 — validated).
// Closed-form qgate (validated vs state-vector sim in R4):
//   gate_w = (w<7 ? cos(q_w) : 1) * prod_{j<=w} cos(theta_j + (j==7?q_7:0))
// Lane = b4*16 + gp*8 + w; all cross-lane traffic is DPP (zero waits).
__global__ __launch_bounds__(64) void k_rec8(
    const float* __restrict__ W0, const float* __restrict__ q0,
    const float* __restrict__ W1, const float* __restrict__ q1,
    const float* __restrict__ W2, const float* __restrict__ q2,
    const float* __restrict__ W3, const float* __restrict__ q3,
    const float* __restrict__ pre,
    float* __restrict__ out, int S, int B, int ID)
{
    const int dIn  = ID + 8;
    const int lane = threadIdx.x;
    const int w    = lane & 7;
    const int gp   = (lane >> 3) & 1;
    const int b    = blockIdx.x*4 + (lane >> 4);
    const int bs   = (b < B) ? b : (B - 1);
    const float* Wp[4] = {W0, W1, W2, W3};
    const float* qp[4] = {q0, q1, q2, q3};
    const int g0 = 2*gp, g1 = 2*gp + 1;

    // rotated hidden-weight rows matching ror:k's hx_{(w-k)&7}
    float wrot0[8], wrot1[8];
    #pragma unroll
    for (int k = 0; k < 8; ++k) {
        int j = (w - k) & 7;
        wrot0[k] = Wp[g0][(long)w*dIn + ID + j];
        wrot1[k] = Wp[g1][(long)w*dIn + ID + j];
    }
    const float qv0 = qp[g0][w], qv1 = qp[g1][w];
    const float mult0 = (w < 7) ? __cosf(qv0) : 1.0f;
    const float mult1 = (w < 7) ? __cosf(qv1) : 1.0f;
    const float qadd0 = (w == 7) ? qv0 : 0.0f;
    const float qadd1 = (w == 7) ? qv1 : 0.0f;
    const float ascl = gp ? 2.0f : 1.0f;   // gate 2: tanh = 2*sigm(2x)-1
    const float aoff = gp ? -1.0f : 0.0f;

    float cxw = 0.0f, hxw = 0.0f;
    float hxr[8];
    #pragma unroll
    for (int k = 0; k < 8; ++k) hxr[k] = 0.0f;

    const float2* base = (const float2*)(pre + (long)bs*32 + gp*16 + 2*w);
    const long tstep = (long)B*16;   // float2 units per t

    float2 pf[4];
    #pragma unroll
    for (int d = 0; d < 4; ++d) {
        int tt = (d < S) ? d : (S - 1);
        pf[d] = base[(long)tt*tstep];
    }

    for (int t0 = 0; t0 < S; t0 += 4) {
        #pragma unroll
        for (int d = 0; d < 4; ++d) {          // d compile-time everywhere
            const int t = t0 + d;
            if (t < S) {
                float2 pc = pf[d];             // waits on load from t-4
                int tn = t + 4; if (tn >= S) tn = S - 1;
                pf[d] = base[(long)tn*tstep];  // issue t+4, no wait

                float th0 = pc.x, th1 = pc.y;
                #pragma unroll
                for (int k = 0; k < 8; ++k) {
                    th0 = fmaf(wrot0[k], hxr[k], th0);
                    th1 = fmaf(wrot1[k], hxr[k], th1);
                }
                float P0 = __cosf(th0 + qadd0);
                float P1 = __cosf(th1 + qadd1);

                // inclusive prefix product over the 8 wires (DPP scan)
                float s;
                s = dppf<0x111>(P0); P0 *= (w >= 1) ? s : 1.0f;
                s = dppf<0x111>(P1); P1 *= (w >= 1) ? s : 1.0f;
                s = dppf<0x112>(P0); P0 *= (w >= 2) ? s : 1.0f;
                s = dppf<0x112>(P1); P1 *= (w >= 2) ? s : 1.0f;
                s = dppf<0x114>(P0); P0 *= (w >= 4) ? s : 1.0f;
                s = dppf<0x114>(P1); P1 *= (w >= 4) ? s : 1.0f;

                float act0 = ascl * sigm_f(ascl * (mult0 * P0)) + aoff;
                float act1 = sigm_f(mult1 * P1);

                // swap gate-pairs across octets (same wire): row_ror:8
                float ex0 = dppf<0x128>(act0);
                float ex1 = dppf<0x128>(act1);
                float fv = gp ? ex0  : act0;
                float iv = gp ? ex1  : act1;
                float gv = gp ? act0 : ex0;
                float ov = gp ? act1 : ex1;

                cxw = fv*cxw + iv*gv;
                hxw = ov * tanh_f(cxw);

                if (gp == 0 && b < B) out[((long)t*B + b)*8 + w] = hxw;

                // hx all-gather: hxr[k] = hx_{(w-k)&7} via row_ror:k
                hxr[0] = hxw;
                hxr[1] = dppf<0x121>(hxw);
                hxr[2] = dppf<0x122>(hxw);
                hxr[3] = dppf<0x123>(hxw);
                hxr[4] = dppf<0x124>(hxw);
                hxr[5] = dppf<0x125>(hxw);
                hxr[6] = dppf<0x126>(hxw);
                hxr[7] = dppf<0x127>(hxw);
            }
        }
    }

    if (gp == 0 && b < B) {
        out[((long)S*B + b)*8 + w]     = hxw;
        out[((long)S*B + B + b)*8 + w] = cxw;
    }
}

// ---------------------------------------------------------------------------
// Generic runtime-H recurrence fallback (H <= 32), f32, OLD pre layout.
__global__ __launch_bounds__(64) void k_rec_g(
    const float* __restrict__ pre,
    const float* W0, const float* q0,
    const float* W1, const float* q1,
    const float* W2, const float* q2,
    const float* W3, const float* q3,
    float* __restrict__ out, int S, int B, int ID, int H)
{
    __shared__ float sWh[4*32*32];
    __shared__ float scq[4*32];
    const int dIn = ID + H;
    const int tid = threadIdx.x;
    const int b   = blockIdx.x*64 + tid;
    const float* Wp[4] = {W0, W1, W2, W3};
    const float* qp[4] = {q0, q1, q2, q3};

    for (int idx = tid; idx < 4*H*H; idx += 64) {
        int g = idx / (H*H), r = idx % (H*H);
        int w = r / H, j = r % H;
        sWh[(g*H + w)*H + j] = Wp[g][(long)w*dIn + ID + j];
    }
    for (int idx = tid; idx < 4*H; idx += 64) {
        int g = idx / H, w = idx % H;
        float qv = qp[g][w];
        scq[idx] = (w < H-1) ? __cosf(qv) : qv;
    }
    __syncthreads();
    if (b >= B) return;

    float hx[32], cx[32], gate[4][32], th[32];
    for (int w = 0; w < H; ++w) { hx[w] = 0.0f; cx[w] = 0.0f; }

    for (int t = 0; t < S; ++t) {
        const float* pt = pre + ((long)t*B + b)*4*H;
        for (int g = 0; g < 4; ++g) {
            for (int w = 0; w < H; ++w) {
                float a = pt[g*H + w];
                const float* wrp = &sWh[(g*H + w)*H];
                for (int j = 0; j < H; ++j) a += wrp[j]*hx[j];
                th[w] = a;
            }
            float cum = 1.0f;
            for (int w = 0; w < H-1; ++w) {
                cum *= __cosf(th[w]);
                gate[g][w] = scq[g*H + w] * cum;
            }
            gate[g][H-1] = cum * __cosf(th[H-1] + scq[g*H + H-1]);
        }
        float* orow = out + ((long)t*B + b)*H;
        for (int w = 0; w < H; ++w) {
            float fv = sigm (gate[0][w]);
            float iv = sigm (gate[1][w]);
            float gv = tanh_(gate[2][w]);
            float ov = sigm (gate[3][w]);
            cx[w] = fv*cx[w] + iv*gv;
            hx[w] = ov*tanh_(cx[w]);
            orow[w] = hx[w];
        }
    }
    float* oh = out + ((long)S*B + b)*H;
    float* oc = out + ((long)S*B + B + b)*H;
    for (int w = 0; w < H; ++w) { oh[w] = hx[w]; oc[w] = cx[w]; }
}

static bool derive(long sz[13], long osz, long& S, long& B, long& ID, long& H) {
    H = sz[3];
    long dIn = (H > 0) ? sz[1] / H : 0;
    ID = dIn - H;
    long TB = (ID > 0) ? sz[0] / ID : 0;
    B = (H > 0) ? (osz / H - TB) / 2 : 0;
    S = (B > 0) ? TB / B : 0;
    return (H >= 1 && H <= 32 && ID >= 1 && B >= 1 && S >= 1 &&
            S*B == TB && (S*B + 2*B)*H == osz &&
            dIn*H == sz[1] && TB*ID == sz[0]);
}

extern "C" void kernel_launch(void* const* d_in, const int* in_sizes, int n_in,
                              void* d_out, int out_size, void* d_ws, size_t ws_size,
                              hipStream_t stream) {
    const float* x  = (const float*)d_in[0];
    const float* Wf = (const float*)d_in[1];  const float* bfv = (const float*)d_in[2];  const float* qf = (const float*)d_in[3];
    const float* Wi = (const float*)d_in[4];  const float* biv = (const float*)d_in[5];  const float* qi = (const float*)d_in[6];
    const float* Wg = (const float*)d_in[7];  const float* bgv = (const float*)d_in[8];  const float* qg = (const float*)d_in[9];
    const float* Wo = (const float*)d_in[10]; const float* bov = (const float*)d_in[11]; const float* qo = (const float*)d_in[12];
    float* out = (float*)d_out;

    long S = 0, B = 0, ID = 0, H = 0;
    bool ok = false;
    for (int scale : {1, 4, 2}) {
        long sz[13];
        for (int i = 0; i < 13; ++i) sz[i] = (long)in_sizes[i] / scale;
        long osz = (long)out_size / scale;
        if (derive(sz, osz, S, B, ID, H)) { ok = true; break; }
    }
    if (!ok) { H = 8; ID = 64; B = 256; S = 64; }
    long dIn = ID + H;

    size_t pre_bytes = (size_t)S * 4 * H * B * sizeof(float);
    float* pre = (ws_size >= pre_bytes) ? (float*)d_ws : g_pre_static;

    if (H == 8 && ID == 64) {
        k_pre8<64><<<dim3((unsigned)S, (unsigned)((B + 7) / 8)), dim3(256), 0, stream>>>(
            x, Wf, bfv, Wi, biv, Wg, bgv, Wo, bov, pre, (int)S, (int)B);
        k_rec8<<<dim3((unsigned)((B + 3) / 4)), dim3(64), 0, stream>>>(
            Wf, qf, Wi, qi, Wg, qg, Wo, qo, pre, out, (int)S, (int)B, (int)ID);
    } else {
        int SP = (int)ID + 1;
        size_t lds_bytes = (size_t)(64*SP + 4*H*(dIn + 1) + 4*H) * sizeof(float);
        k_pre_gen<<<dim3((unsigned)S, (unsigned)((B + 63) / 64)), dim3(256), lds_bytes, stream>>>(
            x, Wf, bfv, Wi, biv, Wg, bgv, Wo, bov, pre,
            (int)S, (int)B, (int)ID, (int)H, SP);
        k_rec_g<<<dim3((unsigned)((B + 63) / 64)), dim3(64), 0, stream>>>(
            pre, Wf, qf, Wi, qi, Wg, qg, Wo, qo, out, (int)S, (int)B, (int)ID, (int)H);
    }
}